// Round 9
// baseline (230.340 us; speedup 1.0000x reference)
//
#include <hip/hip_runtime.h>
#include <hip/hip_bf16.h>

#define NB 2
#define LL 2048
#define EE 1024
#define HH 16
#define HDD 64
#define FFD 4096

typedef unsigned short ushort_t;
typedef __attribute__((ext_vector_type(8))) short short8;
typedef __attribute__((ext_vector_type(4))) float f32x4;

constexpr float LN_EPS = 1e-5f;
constexpr float QSCALE = 0.03125f * 1.44269504088896340736f;  // 1/32 * log2(e)

__device__ inline ushort_t f2bf(float f) {
    union { __hip_bfloat16 b; ushort_t u; } v;
    v.b = __float2bfloat16(f);   // native RNE; compiler fuses pairs to cvt_pk
    return v.u;
}
__device__ inline float bf2f(unsigned us) {
    union { unsigned u; float f; } v; v.u = us << 16; return v.f;
}

__device__ inline void gload16(const void* g, void* lds) {
    __builtin_amdgcn_global_load_lds(
        (const __attribute__((address_space(1))) void*)g,
        (__attribute__((address_space(3))) void*)lds, 16, 0, 0);
}

// ---------------------------------------------------------------------------
// K convert: [N,L,H,D] f32 -> [N,H,L,D] bf16.
// ---------------------------------------------------------------------------
__global__ __launch_bounds__(256) void k_cvt(
    const float* __restrict__ in, ushort_t* __restrict__ out)
{
    const int t = threadIdx.x;
    const int g = blockIdx.x * 32 + (t >> 3);          // (n*H+h)*L + l
    const int n = g >> 15, h = (g >> 11) & 15, l2 = g & 2047;
    const int d0 = (t & 7) * 8;
    const float* src = in + ((size_t)(n * LL + l2) * HH + h) * HDD + d0;
    const float4 a = *(const float4*)src;
    const float4 b = *(const float4*)(src + 4);
    uint4 pk;
    pk.x = f2bf(a.x) | ((unsigned)f2bf(a.y) << 16);
    pk.y = f2bf(a.z) | ((unsigned)f2bf(a.w) << 16);
    pk.z = f2bf(b.x) | ((unsigned)f2bf(b.y) << 16);
    pk.w = f2bf(b.z) | ((unsigned)f2bf(b.w) << 16);
    *(uint4*)(out + (size_t)g * HDD + d0) = pk;
}

// ---------------------------------------------------------------------------
// V convert+transpose: [N,L,H,D] f32 -> [N,H,D,L] bf16, kv-permuted columns:
//   phys(c') = ((c'>>5)*2 + ((c'>>2)&1))*16 + ((c'>>3)&3)*4 + (c'&3)
// ---------------------------------------------------------------------------
__global__ __launch_bounds__(256) void v_cvt_t(
    const float* __restrict__ in, ushort_t* __restrict__ out)
{
    __shared__ float T[64][68];
    const int lb = blockIdx.x, h = blockIdx.y, n = blockIdx.z;
    const int t = threadIdx.x;
    const int l0 = lb * 64;
    {
        const int r = t >> 2, c0 = (t & 3) * 16;
        const float* src = in + ((size_t)(n * LL + l0 + r) * HH + h) * HDD + c0;
#pragma unroll
        for (int i = 0; i < 4; ++i)
            *(float4*)&T[r][c0 + 4 * i] = *(const float4*)(src + 4 * i);
    }
    __syncthreads();
    {
        const int d = t >> 2, tq = t & 3;
        unsigned u[8];
#pragma unroll
        for (int k = 0; k < 8; ++k) {
            const int c0 = tq * 16 + 2 * k, c1 = c0 + 1;
            const int p0 = (((c0 >> 5) * 2 + ((c0 >> 2) & 1)) << 4) +
                           (((c0 >> 3) & 3) << 2) + (c0 & 3);
            const int p1 = (((c1 >> 5) * 2 + ((c1 >> 2) & 1)) << 4) +
                           (((c1 >> 3) & 3) << 2) + (c1 & 3);
            u[k] = f2bf(T[p0][d]) | ((unsigned)f2bf(T[p1][d]) << 16);
        }
        ushort_t* dst = out + ((size_t)(n * HH + h) * HDD + d) * LL + l0 + tq * 16;
        uint4 q0; q0.x = u[0]; q0.y = u[1]; q0.z = u[2]; q0.w = u[3];
        uint4 q1; q1.x = u[4]; q1.y = u[5]; q1.z = u[6]; q1.w = u[7];
        *(uint4*)(dst)     = q0;
        *(uint4*)(dst + 8) = q1;
    }
}

// ---------------------------------------------------------------------------
// MFMA flash attention, swapped QK^T, P in registers, no-max softmax,
// row-sum via MFMA ones-column. Counted-vmcnt double buffering (T4) +
// XCD-bijective block mapping (T1). Block = (n,h,64 q), 4 waves x 16 q.
// ---------------------------------------------------------------------------
__global__ __launch_bounds__(256) void attn_mfma(
    const float* __restrict__ Qf,     // [N,L,H,D] f32 (raw query)
    const ushort_t* __restrict__ Kh,  // [N,H,L,D] bf16
    const ushort_t* __restrict__ Vt,  // [N,H,D,L] bf16 kv-permuted
    ushort_t* __restrict__ O)         // [N,L,E] bf16
{
    // XCD mapping: hw slot s -> xcd = s&7 owns heads {xcd, xcd+8}, consecutive qb
    const int s = blockIdx.x;          // grid = 1024
    const int xcd = s & 7, seq = s >> 3;
    const int qb = seq & 31, tt = seq >> 5;      // tt in 0..3
    const int h = ((tt & 1) << 3) | xcd;
    const int n = tt >> 1;

    const int t = threadIdx.x, w = t >> 6, l = t & 63;
    const int lr = l & 15, lg = l >> 4;

    __shared__ __align__(16) ushort_t Ks[2][64 * 64];
    __shared__ __align__(16) ushort_t Vs[2][64 * 64];

    const size_t hbase = ((size_t)n * HH + h) * LL * HDD;
    const size_t vbase = ((size_t)n * HH + h) * HDD * LL;
    const int q0 = qb * 64 + w * 16;

    // Q fragments (B-operand), converted+scaled in-kernel
    short8 bq[2];
#pragma unroll
    for (int ks = 0; ks < 2; ++ks) {
        const float* qsrc = Qf + ((size_t)(n * LL + q0 + lr) * HH + h) * HDD
                               + ks * 32 + lg * 8;
        const float4 a = *(const float4*)qsrc;
        const float4 b = *(const float4*)(qsrc + 4);
        union { short8 s8; unsigned u[4]; } pk;
        pk.u[0] = f2bf(a.x * QSCALE) | ((unsigned)f2bf(a.y * QSCALE) << 16);
        pk.u[1] = f2bf(a.z * QSCALE) | ((unsigned)f2bf(a.w * QSCALE) << 16);
        pk.u[2] = f2bf(b.x * QSCALE) | ((unsigned)f2bf(b.y * QSCALE) << 16);
        pk.u[3] = f2bf(b.z * QSCALE) | ((unsigned)f2bf(b.w * QSCALE) << 16);
        bq[ks] = pk.s8;
    }

    union { short8 s8; ushort_t u[8]; } one_u;
#pragma unroll
    for (int i = 0; i < 8; ++i) one_u.u[i] = 0x3F80;
    const short8 ones = one_u.s8;

    f32x4 acco[4];
#pragma unroll
    for (int dn = 0; dn < 4; ++dn) {
        f32x4 z = {0.f, 0.f, 0.f, 0.f};
        acco[dn] = z;
    }
    f32x4 accp = {0.f, 0.f, 0.f, 0.f};

    const int id0 = w * 2;
#define STAGE(buf, kt)                                                         \
    {                                                                          \
        _Pragma("unroll")                                                      \
        for (int j = 0; j < 2; ++j) {                                          \
            const int id = (id0 + j) * 64 + l;                                 \
            const int r = id >> 3, c = id & 7;                                 \
            const int cs = c ^ (r & 7);                                        \
            gload16(Kh + hbase + (size_t)((kt) * 64 + r) * HDD + cs * 8,       \
                    (void*)(Ks[buf] + (id0 + j) * 512));                       \
            gload16(Vt + vbase + (size_t)r * LL + (kt) * 64 + cs * 8,          \
                    (void*)(Vs[buf] + (id0 + j) * 512));                       \
        }                                                                      \
    }

    constexpr int NT = LL / 64;
    STAGE(0, 0);
    STAGE(1, 1);
    asm volatile("s_waitcnt vmcnt(4)" ::: "memory");   // tile 0 landed
    __builtin_amdgcn_sched_barrier(0);
    __builtin_amdgcn_s_barrier();

    const f32x4 z4 = {0.f, 0.f, 0.f, 0.f};

    for (int kt = 0; kt < NT; ++kt) {
        const int buf = kt & 1;

        // ---- S^T = K Q^T : accs[nk][r] = S[kv=nk*16+lg*4+r][q=q0+lr] ----
        f32x4 accs[4];
        __builtin_amdgcn_s_setprio(1);
        {
            short8 ak[4];
#pragma unroll
            for (int nk = 0; nk < 4; ++nk) {
                const int row = nk * 16 + lr;
                ak[nk] = *(const short8*)(
                    Ks[buf] + row * 64 + ((lg) ^ (row & 7)) * 8);
            }
#pragma unroll
            for (int nk = 0; nk < 4; ++nk)
                accs[nk] = __builtin_amdgcn_mfma_f32_16x16x32_bf16(
                    ak[nk], bq[0], z4, 0, 0, 0);
#pragma unroll
            for (int nk = 0; nk < 4; ++nk) {
                const int row = nk * 16 + lr;
                ak[nk] = *(const short8*)(
                    Ks[buf] + row * 64 + ((4 | lg) ^ (row & 7)) * 8);
            }
#pragma unroll
            for (int nk = 0; nk < 4; ++nk)
                accs[nk] = __builtin_amdgcn_mfma_f32_16x16x32_bf16(
                    ak[nk], bq[1], accs[nk], 0, 0, 0);
        }
        __builtin_amdgcn_s_setprio(0);

        // ---- P = 2^S in registers, pack; pa slot i -> accs[2ks+(i>>2)][i&3]
        float p[4][4];
#pragma unroll
        for (int nk = 0; nk < 4; ++nk)
#pragma unroll
            for (int r = 0; r < 4; ++r) p[nk][r] = exp2f(accs[nk][r]);
        short8 pa[2];
#pragma unroll
        for (int ks = 0; ks < 2; ++ks) {
            union { short8 s8; unsigned u[4]; } pk;
            pk.u[0] = f2bf(p[2*ks][0])   | ((unsigned)f2bf(p[2*ks][1])   << 16);
            pk.u[1] = f2bf(p[2*ks][2])   | ((unsigned)f2bf(p[2*ks][3])   << 16);
            pk.u[2] = f2bf(p[2*ks+1][0]) | ((unsigned)f2bf(p[2*ks+1][1]) << 16);
            pk.u[3] = f2bf(p[2*ks+1][2]) | ((unsigned)f2bf(p[2*ks+1][3]) << 16);
            pa[ks] = pk.s8;
        }

        // ---- O += P V ; row-sum += P @ ones ----
        __builtin_amdgcn_s_setprio(1);
#pragma unroll
        for (int ks = 0; ks < 2; ++ks) {
            short8 bv[4];
#pragma unroll
            for (int dn = 0; dn < 4; ++dn) {
                const int row = dn * 16 + lr;
                bv[dn] = *(const short8*)(
                    Vs[buf] + row * 64 + (((ks << 2) | lg) ^ (row & 7)) * 8);
            }
            accp = __builtin_amdgcn_mfma_f32_16x16x32_bf16(pa[ks], ones, accp,
                                                           0, 0, 0);
#pragma unroll
            for (int dn = 0; dn < 4; ++dn)
                acco[dn] = __builtin_amdgcn_mfma_f32_16x16x32_bf16(
                    pa[ks], bv[dn], acco[dn], 0, 0, 0);
        }
        __builtin_amdgcn_s_setprio(0);

        // ---- T4 counted pipeline: never drain vmcnt to 0 ----
        __builtin_amdgcn_s_barrier();                 // all reads of buf done
        const int kt2 = (kt + 2 < NT) ? kt + 2 : 0;   // clamped dead-stage tail
        STAGE(buf, kt2);
        asm volatile("s_waitcnt vmcnt(4)" ::: "memory");  // tile kt+1 landed
        __builtin_amdgcn_sched_barrier(0);
        __builtin_amdgcn_s_barrier();                 // kt+1 visible block-wide
    }

    // ---- write: accp[r] is the full row-sum for q = q0+lg*4+r ----
#pragma unroll
    for (int r = 0; r < 4; ++r) {
        const float invl = 1.f / accp[r];
        const int qq = q0 + lg * 4 + r;
        ushort_t* dst = O + (size_t)(n * LL + qq) * EE + h * HDD + lr;
#pragma unroll
        for (int dn = 0; dn < 4; ++dn)
            dst[dn * 16] = f2bf(acco[dn][r] * invl);
    }
#undef STAGE
}

// ---------------------------------------------------------------------------
// Transpose+convert: in f32 [K][N] -> out bf16 [N][K]
// ---------------------------------------------------------------------------
__global__ __launch_bounds__(256) void tcvt(
    const float* __restrict__ in, ushort_t* __restrict__ out, int K, int N)
{
    __shared__ float T[32][36];
    const int n0 = blockIdx.x * 32, k0 = blockIdx.y * 32;
    const int r = threadIdx.x >> 3, c4 = (threadIdx.x & 7) * 4;
    const float4 v = *(const float4*)(in + (size_t)(k0 + r) * N + n0 + c4);
    T[r][c4] = v.x; T[r][c4 + 1] = v.y; T[r][c4 + 2] = v.z; T[r][c4 + 3] = v.w;
    __syncthreads();
    const unsigned a = f2bf(T[c4][r])     | ((unsigned)f2bf(T[c4 + 1][r]) << 16);
    const unsigned b = f2bf(T[c4 + 2][r]) | ((unsigned)f2bf(T[c4 + 3][r]) << 16);
    uint2 pk; pk.x = a; pk.y = b;
    *(uint2*)(out + (size_t)(n0 + r) * K + k0 + c4) = pk;
}

// ---------------------------------------------------------------------------
// 2-phase bf16 MFMA GEMM, counted-vmcnt pipeline (T4), optional split-K.
// ---------------------------------------------------------------------------
template <int BM, int BN, bool RELU, bool RES, bool OBF16, bool BIAS, int KSPLIT>
__global__ __launch_bounds__(256) void mfma_gemm(
    const ushort_t* __restrict__ A, const ushort_t* __restrict__ Bt,
    const float* __restrict__ bias, const float* __restrict__ res,
    void* __restrict__ Cout, int M, int N, int K)
{
    constexpr int LA = BM / 64;
    constexpr int LB = BN / 64;
    constexpr int LT = LA + LB;          // loads per stage
    constexpr int WM = BM / 2, WN = BN / 2;
    constexpr int MI = WM / 16, NI = WN / 16;

    __shared__ __align__(16) ushort_t As[2][BM * 32];
    __shared__ __align__(16) ushort_t Bs[2][BN * 32];

    const int t = threadIdx.x;
    const int w = t >> 6, l = t & 63;

    const int z = (KSPLIT > 1) ? blockIdx.z : 0;
    const int Keff = K / KSPLIT;
    const size_t kb = (size_t)z * Keff;

    const int gx = gridDim.x;
    const int nwg = gx * gridDim.y;
    const int bid = blockIdx.y * gx + blockIdx.x;
    int tile = bid;
    if ((nwg & 7) == 0) tile = (bid & 7) * (nwg >> 3) + (bid >> 3);
    const int bx = tile % gx, by = tile / gx;

    const int brow = by * BM, bcol = bx * BN;
    const int wr = w >> 1, wc = w & 1;

    const int sr = l >> 2;
    const int scd = l & 3;
    const int scg = (scd - (sr >> 1)) & 3;

    const ushort_t* pA[LA];
    const ushort_t* pB[LB];
#pragma unroll
    for (int i = 0; i < LA; ++i)
        pA[i] = A + (size_t)(brow + (w * LA + i) * 16 + sr) * K + kb + scg * 8;
#pragma unroll
    for (int i = 0; i < LB; ++i)
        pB[i] = Bt + (size_t)(bcol + (w * LB + i) * 16 + sr) * K + kb + scg * 8;

#define GSTAGE(b, k0)                                                          \
    {                                                                          \
        _Pragma("unroll")                                                      \
        for (int i = 0; i < LA; ++i)                                           \
            gload16(pA[i] + (k0), (void*)(As[b] + (w * LA + i) * 512));        \
        _Pragma("unroll")                                                      \
        for (int i = 0; i < LB; ++i)                                           \
            gload16(pB[i] + (k0), (void*)(Bs[b] + (w * LB + i) * 512));        \
    }
#define WAIT_LT()                                                              \
    {                                                                          \
        if constexpr (LT == 2)      asm volatile("s_waitcnt vmcnt(2)":::"memory"); \
        else if constexpr (LT == 3) asm volatile("s_waitcnt vmcnt(3)":::"memory"); \
        else                        asm volatile("s_waitcnt vmcnt(4)":::"memory"); \
        __builtin_amdgcn_sched_barrier(0);                                     \
    }

    const int fr = l & 15, fg = l >> 4;
    const int chunk = (fg + (fr >> 1)) & 3;
    const int aoff = (wr * WM + fr) * 32 + chunk * 8;
    const int boff = (wc * WN + fr) * 32 + chunk * 8;

    f32x4 acc[MI][NI];
#pragma unroll
    for (int mi = 0; mi < MI; ++mi)
#pragma unroll
        for (int ni = 0; ni < NI; ++ni) {
            f32x4 zz = {0.f, 0.f, 0.f, 0.f};
            acc[mi][ni] = zz;
        }

    const int nk = Keff / 32;
    GSTAGE(0, 0);
    GSTAGE(1, 32);
    WAIT_LT();                               // tile 0 landed
    __builtin_amdgcn_s_barrier();

    for (int kt = 0; kt < nk; ++kt) {
        const int cur = kt & 1;

        short8 af[MI], bf[NI];
#pragma unroll
        for (int mi = 0; mi < MI; ++mi)
            af[mi] = *(const short8*)(As[cur] + aoff + mi * 16 * 32);
#pragma unroll
        for (int ni = 0; ni < NI; ++ni)
            bf[ni] = *(const short8*)(Bs[cur] + boff + ni * 16 * 32);
        __builtin_amdgcn_s_setprio(1);
#pragma unroll
        for (int mi = 0; mi < MI; ++mi)
#pragma unroll
            for (int ni = 0; ni < NI; ++ni)
                acc[mi][ni] = __builtin_amdgcn_mfma_f32_16x16x32_bf16(
                    af[mi], bf[ni], acc[mi][ni], 0, 0, 0);
        __builtin_amdgcn_s_setprio(0);

        __builtin_amdgcn_s_barrier();        // all reads of cur done
        const int k2 = (kt + 2 < nk) ? (kt + 2) * 32 : 0;
        GSTAGE(cur, k2);
        WAIT_LT();                           // tile kt+1 landed
        __builtin_amdgcn_s_barrier();        // visible block-wide
    }

    const int crow0 = brow + wr * WM + fg * 4;
    const int ccol0 = bcol + wc * WN + fr;
    ushort_t* Cb = (ushort_t*)Cout + (size_t)z * M * N;
#pragma unroll
    for (int mi = 0; mi < MI; ++mi) {
#pragma unroll
        for (int ni = 0; ni < NI; ++ni) {
            const int col = ccol0 + ni * 16;
            const float bv = BIAS ? bias[col] : 0.f;
#pragma unroll
            for (int r = 0; r < 4; ++r) {
                const int row = crow0 + mi * 16 + r;
                float v = acc[mi][ni][r] + bv;
                if (RES) v += res[(size_t)row * N + col];
                if (RELU) v = fmaxf(v, 0.f);
                if (OBF16) Cb[(size_t)row * N + col] = f2bf(v);
                else       ((float*)Cout)[(size_t)row * N + col] = v;
            }
        }
    }
#undef GSTAGE
#undef WAIT_LT
}

// ---------------------------------------------------------------------------
// 8-phase 256x256 bf16 MFMA GEMM (ffn1): C = relu(A @ Bt^T + bias), bf16 out.
// ---------------------------------------------------------------------------
__global__ __launch_bounds__(512, 2) void gemm8p(
    const ushort_t* __restrict__ A, const ushort_t* __restrict__ Bt,
    const float* __restrict__ bias, ushort_t* __restrict__ C,
    int M, int N, int K)
{
    __shared__ __align__(16) ushort_t L[2][4][256 * 32];  // 128 KiB

    const int tid = threadIdx.x;
    const int w = tid >> 6, l = tid & 63;
    const int fr = l & 15, lg = l >> 4;
    const int wr = w >> 2, wc = w & 3;

    const int gx = gridDim.x;
    const int nwg = gx * gridDim.y;
    const int bid = blockIdx.y * gx + blockIdx.x;
    int tile = bid;
    if ((nwg & 7) == 0) tile = (bid & 7) * (nwg >> 3) + (bid >> 3);
    const int bx = tile % gx, by = tile / gx;
    const int brow = by * 256, bcol = bx * 256;

    const int NT = K >> 6;
    const int UMAX = NT << 2;

#define STAGE8(u)                                                              \
    if ((u) < UMAX) {                                                          \
        const int tt = (u) >> 2, slot = (u) & 3;                               \
        const int op = slot & 1, kh = slot >> 1;                               \
        const ushort_t* sp = op ? Bt : A;                                      \
        const int rb = op ? bcol : brow;                                       \
        ushort_t* db = (ushort_t*)L[tt & 1][slot];                             \
        _Pragma("unroll")                                                      \
        for (int j = 0; j < 2; ++j) {                                          \
            const int id = j * 512 + tid;                                      \
            const int row = id >> 2, c = id & 3;                               \
            const int cs = c ^ ((row >> 1) & 3);                               \
            gload16(sp + (size_t)(rb + row) * K + tt * 64 + kh * 32 + cs * 8,  \
                    (void*)(db + id * 8));                                     \
        }                                                                      \
    }

    f32x4 acc[8][4];
#pragma unroll
    for (int i = 0; i < 8; ++i)
#pragma unroll
        for (int g = 0; g < 4; ++g) { f32x4 zz = {0.f,0.f,0.f,0.f}; acc[i][g] = zz; }

#pragma unroll
    for (int u = 0; u < 6; ++u) STAGE8(u);
    asm volatile("s_waitcnt vmcnt(4)" ::: "memory");
    __builtin_amdgcn_sched_barrier(0);
    __builtin_amdgcn_s_barrier();

    const int iters = NT >> 1;
    for (int it = 0; it < iters; ++it) {
#pragma unroll
        for (int p = 0; p < 8; ++p) {
            STAGE8(it * 8 + p + 6);
            const int d  = p >> 2;
            const int mh = p & 1, kh = (p >> 1) & 1;
            short8 af[4], bfr[4];
#pragma unroll
            for (int f = 0; f < 4; ++f) {
                const int row = wr * 128 + (mh * 4 + f) * 16 + fr;
                const int ch = lg ^ ((row >> 1) & 3);
                af[f] = *(const short8*)(&L[d][kh * 2][row * 32 + ch * 8]);
            }
#pragma unroll
            for (int g = 0; g < 4; ++g) {
                const int row = wc * 64 + g * 16 + fr;
                const int ch = lg ^ ((row >> 1) & 3);
                bfr[g] = *(const short8*)(&L[d][kh * 2 + 1][row * 32 + ch * 8]);
            }
            __builtin_amdgcn_s_barrier();
            __builtin_amdgcn_s_setprio(1);
#pragma unroll
            for (int f = 0; f < 4; ++f)
#pragma unroll
                for (int g = 0; g < 4; ++g)
                    acc[mh * 4 + f][g] = __builtin_amdgcn_mfma_f32_16x16x32_bf16(
                        af[f], bfr[g], acc[mh * 4 + f][g], 0, 0, 0);
            __builtin_amdgcn_s_setprio(0);
            if (p == 3 || p == 7) {
                asm volatile("s_waitcnt vmcnt(4)" ::: "memory");
                __builtin_amdgcn_sched_barrier(0);
            }
            __builtin_amdgcn_s_barrier();
        }
    }

#pragma unroll
    for (int mi = 0; mi < 8; ++mi) {
#pragma unroll
        for (int g = 0; g < 4; ++g) {
            const int col = bcol + wc * 64 + g * 16 + fr;
            const float bv = bias[col];
#pragma unroll
            for (int r = 0; r < 4; ++r) {
                const int row = brow + wr * 128 + mi * 16 + lg * 4 + r;
                const float v = fmaxf(acc[mi][g][r] + bv, 0.f);
                C[(size_t)row * N + col] = f2bf(v);
            }
        }
    }
#undef STAGE8
}

// ---------------------------------------------------------------------------
// LN1: bf16 in -> bf16 out (x = LN(preX))
// ---------------------------------------------------------------------------
__global__ __launch_bounds__(256) void ln_mid(
    const ushort_t* __restrict__ in, const float* __restrict__ g,
    const float* __restrict__ b, ushort_t* __restrict__ out)
{
    const int row = blockIdx.x;
    const int t = threadIdx.x;
    const uint2 u = ((const uint2*)(in + (size_t)row * EE))[t];
    float x[4];
    x[0] = bf2f(u.x & 0xffff); x[1] = bf2f(u.x >> 16);
    x[2] = bf2f(u.y & 0xffff); x[3] = bf2f(u.y >> 16);

    float s = 0.f, ss = 0.f;
#pragma unroll
    for (int i = 0; i < 4; ++i) { s += x[i]; ss += x[i] * x[i]; }
#pragma unroll
    for (int o = 1; o < 64; o <<= 1) {
        s  += __shfl_xor(s, o, 64);
        ss += __shfl_xor(ss, o, 64);
    }
    __shared__ float sm[8];
    const int wid = t >> 6;
    if ((t & 63) == 0) { sm[wid * 2] = s; sm[wid * 2 + 1] = ss; }
    __syncthreads();
    const float stot  = sm[0] + sm[2] + sm[4] + sm[6];
    const float sstot = sm[1] + sm[3] + sm[5] + sm[7];
    const float mu  = stot * (1.f / EE);
    const float inv = rsqrtf(sstot * (1.f / EE) - mu * mu + LN_EPS);

    const float4 gg = ((const float4*)g)[t];
    const float4 bb = ((const float4*)b)[t];
    uint2 pk;
    pk.x = f2bf((x[0] - mu) * inv * gg.x + bb.x) |
           ((unsigned)f2bf((x[1] - mu) * inv * gg.y + bb.y) << 16);
    pk.y = f2bf((x[2] - mu) * inv * gg.z + bb.z) |
           ((unsigned)f2bf((x[3] - mu) * inv * gg.w + bb.w) << 16);
    ((uint2*)(out + (size_t)row * EE))[t] = pk;
}

// ---------------------------------------------------------------------------
// LN2: out = LN(y0 + y1 + b2 + x), y0/y1/x bf16, out f32.
// ---------------------------------------------------------------------------
__global__ __launch_bounds__(256) void ln_out(
    const ushort_t* __restrict__ y0, const ushort_t* __restrict__ y1,
    const ushort_t* __restrict__ xb, const float* __restrict__ b2,
    const float* __restrict__ g, const float* __restrict__ be,
    float* __restrict__ out)
{
    const int row = blockIdx.x;
    const int t = threadIdx.x;
    const size_t off = (size_t)row * EE;
    const uint2 a = ((const uint2*)(y0 + off))[t];
    const uint2 b = ((const uint2*)(y1 + off))[t];
    const uint2 c = ((const uint2*)(xb + off))[t];
    const float4 bb2 = ((const float4*)b2)[t];
    float x[4];
    x[0] = bf2f(a.x & 0xffff) + bf2f(b.x & 0xffff) + bf2f(c.x & 0xffff) + bb2.x;
    x[1] = bf2f(a.x >> 16)    + bf2f(b.x >> 16)    + bf2f(c.x >> 16)    + bb2.y;
    x[2] = bf2f(a.y & 0xffff) + bf2f(b.y & 0xffff) + bf2f(c.y & 0xffff) + bb2.z;
    x[3] = bf2f(a.y >> 16)    + bf2f(b.y >> 16)    + bf2f(c.y >> 16)    + bb2.w;

    float s = 0.f, ss = 0.f;
#pragma unroll
    for (int i = 0; i < 4; ++i) { s += x[i]; ss += x[i] * x[i]; }
#pragma unroll
    for (int o = 1; o < 64; o <<= 1) {
        s  += __shfl_xor(s, o, 64);
        ss += __shfl_xor(ss, o, 64);
    }
    __shared__ float sm[8];
    const int wid = t >> 6;
    if ((t & 63) == 0) { sm[wid * 2] = s; sm[wid * 2 + 1] = ss; }
    __syncthreads();
    const float stot  = sm[0] + sm[2] + sm[4] + sm[6];
    const float sstot = sm[1] + sm[3] + sm[5] + sm[7];
    const float mu  = stot * (1.f / EE);
    const float inv = rsqrtf(sstot * (1.f / EE) - mu * mu + LN_EPS);

    const float4 gg = ((const float4*)g)[t];
    const float4 bb = ((const float4*)be)[t];
    float4 o;
    o.x = (x[0] - mu) * inv * gg.x + bb.x;
    o.y = (x[1] - mu) * inv * gg.y + bb.y;
    o.z = (x[2] - mu) * inv * gg.z + bb.z;
    o.w = (x[3] - mu) * inv * gg.w + bb.w;
    ((float4*)(out + off))[t] = o;
}

// ---------------------------------------------------------------------------
extern "C" void kernel_launch(void* const* d_in, const int* in_sizes, int n_in,
                              void* d_out, int out_size, void* d_ws, size_t ws_size,
                              hipStream_t stream) {
    (void)in_sizes; (void)n_in; (void)out_size; (void)ws_size;
    const float* value = (const float*)d_in[0];
    const float* key   = (const float*)d_in[1];
    const float* query = (const float*)d_in[2];
    const float* w_out = (const float*)d_in[3];
    const float* b_out = (const float*)d_in[4];
    const float* w1    = (const float*)d_in[5];
    const float* b1    = (const float*)d_in[6];
    const float* w2    = (const float*)d_in[7];
    const float* b2    = (const float*)d_in[8];
    const float* g1    = (const float*)d_in[9];
    const float* be1   = (const float*)d_in[10];
    const float* g2    = (const float*)d_in[11];
    const float* be2   = (const float*)d_in[12];
    float* out = (float*)d_out;

    const int M = NB * LL;  // 4096
    char* base = (char*)d_ws;
    ushort_t* attn_bf = (ushort_t*)(base);                      //  8 MB
    ushort_t* x_bf    = (ushort_t*)(base + (8ull  << 20));      //  8 MB
    char*     hregion = base + (16ull << 20);                   // 32 MB
    ushort_t* h_bf    = (ushort_t*)hregion;                     //  (post-attn)
    ushort_t* Kh      = (ushort_t*)(hregion);                   //  8 MB (pre-attn)
    ushort_t* Vt      = (ushort_t*)(hregion + (8ull  << 20));   //  8 MB
    ushort_t* preX_bf = (ushort_t*)(base + (48ull << 20));      //  8 MB
    ushort_t* y01     = (ushort_t*)(base + (56ull << 20));      // 16 MB (2 partials)
    ushort_t* w0T     = (ushort_t*)(base + (72ull << 20));      //  2 MB
    ushort_t* w1T     = (ushort_t*)(base + (74ull << 20));      //  8 MB
    ushort_t* w2T     = (ushort_t*)(base + (82ull << 20));      //  8 MB (ends 90)

    tcvt<<<dim3(EE / 32, EE / 32), 256, 0, stream>>>(w_out, w0T, EE, EE);
    tcvt<<<dim3(FFD / 32, EE / 32), 256, 0, stream>>>(w1, w1T, EE, FFD);
    tcvt<<<dim3(EE / 32, FFD / 32), 256, 0, stream>>>(w2, w2T, FFD, EE);

    k_cvt<<<NB * HH * LL / 32, 256, 0, stream>>>(key, Kh);
    v_cvt_t<<<dim3(LL / 64, HH, NB), 256, 0, stream>>>(value, Vt);

    attn_mfma<<<dim3(NB * HH * LL / 64), 256, 0, stream>>>(query, Kh, Vt,
                                                           attn_bf);

    // proj: [4096,1024] = attn_bf @ w_outT + b_out + query -> bf16 preX
    mfma_gemm<128, 64, false, true, true, true, 1>
        <<<dim3(EE / 64, M / 128), 256, 0, stream>>>(attn_bf, w0T, b_out, query,
                                                     preX_bf, M, EE, EE);
    ln_mid<<<M, 256, 0, stream>>>(preX_bf, g1, be1, x_bf);

    // ffn1: [4096,4096] = relu(x_bf @ w1T + b1), bf16 out (8-phase, 256 blocks)
    gemm8p<<<dim3(FFD / 256, M / 256), 512, 0, stream>>>(x_bf, w1T, b1, h_bf,
                                                         M, FFD, EE);
    // ffn2: split-K=2 -> two bf16 partials (no bias/res; LN2 fuses them)
    mfma_gemm<128, 64, false, false, true, false, 2>
        <<<dim3(EE / 64, M / 128, 2), 256, 0, stream>>>(h_bf, w2T, nullptr,
                                                        nullptr, y01, M, EE, FFD);
    ln_out<<<M, 256, 0, stream>>>(y01, y01 + (size_t)M * EE, x_bf, b2, g2, be2,
                                  out);
}

// Round 10
// 211.538 us; speedup vs baseline: 1.0889x; 1.0889x over previous
//
#include <hip/hip_runtime.h>
#include <hip/hip_bf16.h>

#define NB 2
#define LL 2048
#define EE 1024
#define HH 16
#define HDD 64
#define FFD 4096

typedef unsigned short ushort_t;
typedef __attribute__((ext_vector_type(8))) short short8;
typedef __attribute__((ext_vector_type(4))) float f32x4;

constexpr float LN_EPS = 1e-5f;
constexpr float QSCALE = 0.03125f * 1.44269504088896340736f;  // 1/32 * log2(e)

__device__ inline ushort_t f2bf(float f) {
    union { __hip_bfloat16 b; ushort_t u; } v;
    v.b = __float2bfloat16(f);
    return v.u;
}
__device__ inline float bf2f(unsigned us) {
    union { unsigned u; float f; } v; v.u = us << 16; return v.f;
}
// pack trunc-bf16(lo) | trunc-bf16(hi)<<16 in ONE v_perm_b32
__device__ inline unsigned pk_hi16(float lo, float hi) {
    const unsigned sel = 0x07060302u;
    unsigned r;
    asm("v_perm_b32 %0, %1, %2, %3" : "=v"(r) : "v"(hi), "v"(lo), "s"(sel));
    return r;
}

__device__ inline void gload16(const void* g, void* lds) {
    __builtin_amdgcn_global_load_lds(
        (const __attribute__((address_space(1))) void*)g,
        (__attribute__((address_space(3))) void*)lds, 16, 0, 0);
}

// ---------------------------------------------------------------------------
// K convert: [N,L,H,D] f32 -> [N,H,L,D] bf16.
// ---------------------------------------------------------------------------
__global__ __launch_bounds__(256) void k_cvt(
    const float* __restrict__ in, ushort_t* __restrict__ out)
{
    const int t = threadIdx.x;
    const int g = blockIdx.x * 32 + (t >> 3);          // (n*H+h)*L + l
    const int n = g >> 15, h = (g >> 11) & 15, l2 = g & 2047;
    const int d0 = (t & 7) * 8;
    const float* src = in + ((size_t)(n * LL + l2) * HH + h) * HDD + d0;
    const float4 a = *(const float4*)src;
    const float4 b = *(const float4*)(src + 4);
    uint4 pk;
    pk.x = f2bf(a.x) | ((unsigned)f2bf(a.y) << 16);
    pk.y = f2bf(a.z) | ((unsigned)f2bf(a.w) << 16);
    pk.z = f2bf(b.x) | ((unsigned)f2bf(b.y) << 16);
    pk.w = f2bf(b.z) | ((unsigned)f2bf(b.w) << 16);
    *(uint4*)(out + (size_t)g * HDD + d0) = pk;
}

// ---------------------------------------------------------------------------
// V convert+transpose: [N,L,H,D] f32 -> [N,H,D,L] bf16, kv-permuted columns:
//   phys(c') = ((c'>>5)*2 + ((c'>>2)&1))*16 + ((c'>>3)&3)*4 + (c'&3)
// ---------------------------------------------------------------------------
__global__ __launch_bounds__(256) void v_cvt_t(
    const float* __restrict__ in, ushort_t* __restrict__ out)
{
    __shared__ float T[64][68];
    const int lb = blockIdx.x, h = blockIdx.y, n = blockIdx.z;
    const int t = threadIdx.x;
    const int l0 = lb * 64;
    {
        const int r = t >> 2, c0 = (t & 3) * 16;
        const float* src = in + ((size_t)(n * LL + l0 + r) * HH + h) * HDD + c0;
#pragma unroll
        for (int i = 0; i < 4; ++i)
            *(float4*)&T[r][c0 + 4 * i] = *(const float4*)(src + 4 * i);
    }
    __syncthreads();
    {
        const int d = t >> 2, tq = t & 3;
        unsigned u[8];
#pragma unroll
        for (int k = 0; k < 8; ++k) {
            const int c0 = tq * 16 + 2 * k, c1 = c0 + 1;
            const int p0 = (((c0 >> 5) * 2 + ((c0 >> 2) & 1)) << 4) +
                           (((c0 >> 3) & 3) << 2) + (c0 & 3);
            const int p1 = (((c1 >> 5) * 2 + ((c1 >> 2) & 1)) << 4) +
                           (((c1 >> 3) & 3) << 2) + (c1 & 3);
            u[k] = f2bf(T[p0][d]) | ((unsigned)f2bf(T[p1][d]) << 16);
        }
        ushort_t* dst = out + ((size_t)(n * HH + h) * HDD + d) * LL + l0 + tq * 16;
        uint4 q0; q0.x = u[0]; q0.y = u[1]; q0.z = u[2]; q0.w = u[3];
        uint4 q1; q1.x = u[4]; q1.y = u[5]; q1.z = u[6]; q1.w = u[7];
        *(uint4*)(dst)     = q0;
        *(uint4*)(dst + 8) = q1;
    }
}

// ---------------------------------------------------------------------------
// MFMA flash attention, swapped QK^T, P in registers (v_perm trunc pack),
// no-max softmax via native v_exp, row-sum via MFMA ones-column.
// Counted-vmcnt dbuf + XCD-bijective mapping. Block = (n,h,64 q), 4 waves.
// ---------------------------------------------------------------------------
__global__ __launch_bounds__(256) void attn_mfma(
    const float* __restrict__ Qf,     // [N,L,H,D] f32 (raw query)
    const ushort_t* __restrict__ Kh,  // [N,H,L,D] bf16
    const ushort_t* __restrict__ Vt,  // [N,H,D,L] bf16 kv-permuted
    ushort_t* __restrict__ O)         // [N,L,E] bf16
{
    // XCD mapping: xcd = s&7 owns heads {xcd, xcd+8}, consecutive qb
    const int s = blockIdx.x;          // grid = 1024
    const int xcd = s & 7, seq = s >> 3;
    const int qb = seq & 31, tt = seq >> 5;
    const int h = ((tt & 1) << 3) | xcd;
    const int n = tt >> 1;

    const int t = threadIdx.x, w = t >> 6, l = t & 63;
    const int lr = l & 15, lg = l >> 4;

    __shared__ __align__(16) ushort_t Ks[2][64 * 64];
    __shared__ __align__(16) ushort_t Vs[2][64 * 64];

    const size_t hbase = ((size_t)n * HH + h) * LL * HDD;
    const size_t vbase = ((size_t)n * HH + h) * HDD * LL;
    const int q0 = qb * 64 + w * 16;

    // Q fragments (B-operand), converted+scaled in-kernel (RNE, one-time)
    short8 bq[2];
#pragma unroll
    for (int ks = 0; ks < 2; ++ks) {
        const float* qsrc = Qf + ((size_t)(n * LL + q0 + lr) * HH + h) * HDD
                               + ks * 32 + lg * 8;
        const float4 a = *(const float4*)qsrc;
        const float4 b = *(const float4*)(qsrc + 4);
        union { short8 s8; unsigned u[4]; } pk;
        pk.u[0] = f2bf(a.x * QSCALE) | ((unsigned)f2bf(a.y * QSCALE) << 16);
        pk.u[1] = f2bf(a.z * QSCALE) | ((unsigned)f2bf(a.w * QSCALE) << 16);
        pk.u[2] = f2bf(b.x * QSCALE) | ((unsigned)f2bf(b.y * QSCALE) << 16);
        pk.u[3] = f2bf(b.z * QSCALE) | ((unsigned)f2bf(b.w * QSCALE) << 16);
        bq[ks] = pk.s8;
    }

    union { short8 s8; ushort_t u[8]; } one_u;
#pragma unroll
    for (int i = 0; i < 8; ++i) one_u.u[i] = 0x3F80;
    const short8 ones = one_u.s8;

    f32x4 acco[4];
#pragma unroll
    for (int dn = 0; dn < 4; ++dn) {
        f32x4 z = {0.f, 0.f, 0.f, 0.f};
        acco[dn] = z;
    }
    f32x4 accp = {0.f, 0.f, 0.f, 0.f};

    const int id0 = w * 2;
#define STAGE(buf, kt)                                                         \
    {                                                                          \
        _Pragma("unroll")                                                      \
        for (int j = 0; j < 2; ++j) {                                          \
            const int id = (id0 + j) * 64 + l;                                 \
            const int r = id >> 3, c = id & 7;                                 \
            const int cs = c ^ (r & 7);                                        \
            gload16(Kh + hbase + (size_t)((kt) * 64 + r) * HDD + cs * 8,       \
                    (void*)(Ks[buf] + (id0 + j) * 512));                       \
            gload16(Vt + vbase + (size_t)r * LL + (kt) * 64 + cs * 8,          \
                    (void*)(Vs[buf] + (id0 + j) * 512));                       \
        }                                                                      \
    }

    constexpr int NT = LL / 64;
    STAGE(0, 0);
    STAGE(1, 1);
    asm volatile("s_waitcnt vmcnt(4)" ::: "memory");   // tile 0 landed
    __builtin_amdgcn_sched_barrier(0);
    __builtin_amdgcn_s_barrier();

    const f32x4 z4 = {0.f, 0.f, 0.f, 0.f};

    for (int kt = 0; kt < NT; ++kt) {
        const int buf = kt & 1;

        // ---- S^T = K Q^T : accs[nk][r] = S[kv=nk*16+lg*4+r][q=q0+lr] ----
        f32x4 accs[4];
        __builtin_amdgcn_s_setprio(1);
        {
            short8 ak[4];
#pragma unroll
            for (int nk = 0; nk < 4; ++nk) {
                const int row = nk * 16 + lr;
                ak[nk] = *(const short8*)(
                    Ks[buf] + row * 64 + ((lg) ^ (row & 7)) * 8);
            }
#pragma unroll
            for (int nk = 0; nk < 4; ++nk)
                accs[nk] = __builtin_amdgcn_mfma_f32_16x16x32_bf16(
                    ak[nk], bq[0], z4, 0, 0, 0);
#pragma unroll
            for (int nk = 0; nk < 4; ++nk) {
                const int row = nk * 16 + lr;
                ak[nk] = *(const short8*)(
                    Ks[buf] + row * 64 + ((4 | lg) ^ (row & 7)) * 8);
            }
#pragma unroll
            for (int nk = 0; nk < 4; ++nk)
                accs[nk] = __builtin_amdgcn_mfma_f32_16x16x32_bf16(
                    ak[nk], bq[1], accs[nk], 0, 0, 0);
        }
        __builtin_amdgcn_s_setprio(0);

        // ---- P = 2^S (native v_exp), v_perm trunc-pack straight to bf16.
        //      pa slot i -> accs[2ks+(i>>2)][i&3]; trunc is consistent in
        //      numerator (PV) and denominator (ones-MFMA) -> self-normalizing.
        float p[4][4];
#pragma unroll
        for (int nk = 0; nk < 4; ++nk)
#pragma unroll
            for (int r = 0; r < 4; ++r)
                p[nk][r] = __builtin_amdgcn_exp2f(accs[nk][r]);
        short8 pa[2];
#pragma unroll
        for (int ks = 0; ks < 2; ++ks) {
            union { short8 s8; unsigned u[4]; } pk;
            pk.u[0] = pk_hi16(p[2*ks][0],   p[2*ks][1]);
            pk.u[1] = pk_hi16(p[2*ks][2],   p[2*ks][3]);
            pk.u[2] = pk_hi16(p[2*ks+1][0], p[2*ks+1][1]);
            pk.u[3] = pk_hi16(p[2*ks+1][2], p[2*ks+1][3]);
            pa[ks] = pk.s8;
        }

        // ---- O += P V ; row-sum += P @ ones ----
        __builtin_amdgcn_s_setprio(1);
#pragma unroll
        for (int ks = 0; ks < 2; ++ks) {
            short8 bv[4];
#pragma unroll
            for (int dn = 0; dn < 4; ++dn) {
                const int row = dn * 16 + lr;
                bv[dn] = *(const short8*)(
                    Vs[buf] + row * 64 + (((ks << 2) | lg) ^ (row & 7)) * 8);
            }
            accp = __builtin_amdgcn_mfma_f32_16x16x32_bf16(pa[ks], ones, accp,
                                                           0, 0, 0);
#pragma unroll
            for (int dn = 0; dn < 4; ++dn)
                acco[dn] = __builtin_amdgcn_mfma_f32_16x16x32_bf16(
                    pa[ks], bv[dn], acco[dn], 0, 0, 0);
        }
        __builtin_amdgcn_s_setprio(0);

        // ---- counted pipeline: never drain vmcnt to 0 ----
        __builtin_amdgcn_s_barrier();                 // all reads of buf done
        const int kt2 = (kt + 2) & (NT - 1);          // dead-load wrap at tail
        STAGE(buf, kt2);
        asm volatile("s_waitcnt vmcnt(4)" ::: "memory");  // tile kt+1 landed
        __builtin_amdgcn_sched_barrier(0);
        __builtin_amdgcn_s_barrier();                 // kt+1 visible block-wide
    }

    // ---- write: accp[r] is the full row-sum for q = q0+lg*4+r ----
#pragma unroll
    for (int r = 0; r < 4; ++r) {
        const float invl = 1.f / accp[r];
        const int qq = q0 + lg * 4 + r;
        ushort_t* dst = O + (size_t)(n * LL + qq) * EE + h * HDD + lr;
#pragma unroll
        for (int dn = 0; dn < 4; ++dn)
            dst[dn * 16] = f2bf(acco[dn][r] * invl);
    }
#undef STAGE
}

// ---------------------------------------------------------------------------
// Transpose+convert: in f32 [K][N] -> out bf16 [N][K]
// ---------------------------------------------------------------------------
__global__ __launch_bounds__(256) void tcvt(
    const float* __restrict__ in, ushort_t* __restrict__ out, int K, int N)
{
    __shared__ float T[32][36];
    const int n0 = blockIdx.x * 32, k0 = blockIdx.y * 32;
    const int r = threadIdx.x >> 3, c4 = (threadIdx.x & 7) * 4;
    const float4 v = *(const float4*)(in + (size_t)(k0 + r) * N + n0 + c4);
    T[r][c4] = v.x; T[r][c4 + 1] = v.y; T[r][c4 + 2] = v.z; T[r][c4 + 3] = v.w;
    __syncthreads();
    const unsigned a = f2bf(T[c4][r])     | ((unsigned)f2bf(T[c4 + 1][r]) << 16);
    const unsigned b = f2bf(T[c4 + 2][r]) | ((unsigned)f2bf(T[c4 + 3][r]) << 16);
    uint2 pk; pk.x = a; pk.y = b;
    *(uint2*)(out + (size_t)(n0 + r) * K + k0 + c4) = pk;
}

// ---------------------------------------------------------------------------
// 2-phase bf16 MFMA GEMM, counted-vmcnt pipeline, optional split-K.
// ---------------------------------------------------------------------------
template <int BM, int BN, bool RELU, bool RES, bool OBF16, bool BIAS, int KSPLIT>
__global__ __launch_bounds__(256) void mfma_gemm(
    const ushort_t* __restrict__ A, const ushort_t* __restrict__ Bt,
    const float* __restrict__ bias, const float* __restrict__ res,
    void* __restrict__ Cout, int M, int N, int K)
{
    constexpr int LA = BM / 64;
    constexpr int LB = BN / 64;
    constexpr int LT = LA + LB;
    constexpr int WM = BM / 2, WN = BN / 2;
    constexpr int MI = WM / 16, NI = WN / 16;

    __shared__ __align__(16) ushort_t As[2][BM * 32];
    __shared__ __align__(16) ushort_t Bs[2][BN * 32];

    const int t = threadIdx.x;
    const int w = t >> 6, l = t & 63;

    const int z = (KSPLIT > 1) ? blockIdx.z : 0;
    const int Keff = K / KSPLIT;
    const size_t kb = (size_t)z * Keff;

    const int gx = gridDim.x;
    const int nwg = gx * gridDim.y;
    const int bid = blockIdx.y * gx + blockIdx.x;
    int tile = bid;
    if ((nwg & 7) == 0) tile = (bid & 7) * (nwg >> 3) + (bid >> 3);
    const int bx = tile % gx, by = tile / gx;

    const int brow = by * BM, bcol = bx * BN;
    const int wr = w >> 1, wc = w & 1;

    const int sr = l >> 2;
    const int scd = l & 3;
    const int scg = (scd - (sr >> 1)) & 3;

    const ushort_t* pA[LA];
    const ushort_t* pB[LB];
#pragma unroll
    for (int i = 0; i < LA; ++i)
        pA[i] = A + (size_t)(brow + (w * LA + i) * 16 + sr) * K + kb + scg * 8;
#pragma unroll
    for (int i = 0; i < LB; ++i)
        pB[i] = Bt + (size_t)(bcol + (w * LB + i) * 16 + sr) * K + kb + scg * 8;

#define GSTAGE(b, k0)                                                          \
    {                                                                          \
        _Pragma("unroll")                                                      \
        for (int i = 0; i < LA; ++i)                                           \
            gload16(pA[i] + (k0), (void*)(As[b] + (w * LA + i) * 512));        \
        _Pragma("unroll")                                                      \
        for (int i = 0; i < LB; ++i)                                           \
            gload16(pB[i] + (k0), (void*)(Bs[b] + (w * LB + i) * 512));        \
    }
#define WAIT_LT()                                                              \
    {                                                                          \
        if constexpr (LT == 2)      asm volatile("s_waitcnt vmcnt(2)":::"memory"); \
        else if constexpr (LT == 3) asm volatile("s_waitcnt vmcnt(3)":::"memory"); \
        else                        asm volatile("s_waitcnt vmcnt(4)":::"memory"); \
        __builtin_amdgcn_sched_barrier(0);                                     \
    }

    const int fr = l & 15, fg = l >> 4;
    const int chunk = (fg + (fr >> 1)) & 3;
    const int aoff = (wr * WM + fr) * 32 + chunk * 8;
    const int boff = (wc * WN + fr) * 32 + chunk * 8;

    f32x4 acc[MI][NI];
#pragma unroll
    for (int mi = 0; mi < MI; ++mi)
#pragma unroll
        for (int ni = 0; ni < NI; ++ni) {
            f32x4 zz = {0.f, 0.f, 0.f, 0.f};
            acc[mi][ni] = zz;
        }

    const int nk = Keff / 32;
    GSTAGE(0, 0);
    GSTAGE(1, 32);
    WAIT_LT();
    __builtin_amdgcn_s_barrier();

    for (int kt = 0; kt < nk; ++kt) {
        const int cur = kt & 1;

        short8 af[MI], bf[NI];
#pragma unroll
        for (int mi = 0; mi < MI; ++mi)
            af[mi] = *(const short8*)(As[cur] + aoff + mi * 16 * 32);
#pragma unroll
        for (int ni = 0; ni < NI; ++ni)
            bf[ni] = *(const short8*)(Bs[cur] + boff + ni * 16 * 32);
        __builtin_amdgcn_s_setprio(1);
#pragma unroll
        for (int mi = 0; mi < MI; ++mi)
#pragma unroll
            for (int ni = 0; ni < NI; ++ni)
                acc[mi][ni] = __builtin_amdgcn_mfma_f32_16x16x32_bf16(
                    af[mi], bf[ni], acc[mi][ni], 0, 0, 0);
        __builtin_amdgcn_s_setprio(0);

        __builtin_amdgcn_s_barrier();
        const int k2 = (kt + 2 < nk) ? (kt + 2) * 32 : 0;
        GSTAGE(cur, k2);
        WAIT_LT();
        __builtin_amdgcn_s_barrier();
    }

    const int crow0 = brow + wr * WM + fg * 4;
    const int ccol0 = bcol + wc * WN + fr;
    ushort_t* Cb = (ushort_t*)Cout + (size_t)z * M * N;
#pragma unroll
    for (int mi = 0; mi < MI; ++mi) {
#pragma unroll
        for (int ni = 0; ni < NI; ++ni) {
            const int col = ccol0 + ni * 16;
            const float bv = BIAS ? bias[col] : 0.f;
#pragma unroll
            for (int r = 0; r < 4; ++r) {
                const int row = crow0 + mi * 16 + r;
                float v = acc[mi][ni][r] + bv;
                if (RES) v += res[(size_t)row * N + col];
                if (RELU) v = fmaxf(v, 0.f);
                if (OBF16) Cb[(size_t)row * N + col] = f2bf(v);
                else       ((float*)Cout)[(size_t)row * N + col] = v;
            }
        }
    }
#undef GSTAGE
#undef WAIT_LT
}

// ---------------------------------------------------------------------------
// 8-phase 256x256 bf16 MFMA GEMM (ffn1): C = relu(A @ Bt^T + bias), bf16 out.
// ---------------------------------------------------------------------------
__global__ __launch_bounds__(512, 2) void gemm8p(
    const ushort_t* __restrict__ A, const ushort_t* __restrict__ Bt,
    const float* __restrict__ bias, ushort_t* __restrict__ C,
    int M, int N, int K)
{
    __shared__ __align__(16) ushort_t L[2][4][256 * 32];  // 128 KiB

    const int tid = threadIdx.x;
    const int w = tid >> 6, l = tid & 63;
    const int fr = l & 15, lg = l >> 4;
    const int wr = w >> 2, wc = w & 3;

    const int gx = gridDim.x;
    const int nwg = gx * gridDim.y;
    const int bid = blockIdx.y * gx + blockIdx.x;
    int tile = bid;
    if ((nwg & 7) == 0) tile = (bid & 7) * (nwg >> 3) + (bid >> 3);
    const int bx = tile % gx, by = tile / gx;
    const int brow = by * 256, bcol = bx * 256;

    const int NT = K >> 6;
    const int UMAX = NT << 2;

#define STAGE8(u)                                                              \
    if ((u) < UMAX) {                                                          \
        const int tt = (u) >> 2, slot = (u) & 3;                               \
        const int op = slot & 1, kh = slot >> 1;                               \
        const ushort_t* sp = op ? Bt : A;                                      \
        const int rb = op ? bcol : brow;                                       \
        ushort_t* db = (ushort_t*)L[tt & 1][slot];                             \
        _Pragma("unroll")                                                      \
        for (int j = 0; j < 2; ++j) {                                          \
            const int id = j * 512 + tid;                                      \
            const int row = id >> 2, c = id & 3;                               \
            const int cs = c ^ ((row >> 1) & 3);                               \
            gload16(sp + (size_t)(rb + row) * K + tt * 64 + kh * 32 + cs * 8,  \
                    (void*)(db + id * 8));                                     \
        }                                                                      \
    }

    f32x4 acc[8][4];
#pragma unroll
    for (int i = 0; i < 8; ++i)
#pragma unroll
        for (int g = 0; g < 4; ++g) { f32x4 zz = {0.f,0.f,0.f,0.f}; acc[i][g] = zz; }

#pragma unroll
    for (int u = 0; u < 6; ++u) STAGE8(u);
    asm volatile("s_waitcnt vmcnt(4)" ::: "memory");
    __builtin_amdgcn_sched_barrier(0);
    __builtin_amdgcn_s_barrier();

    const int iters = NT >> 1;
    for (int it = 0; it < iters; ++it) {
#pragma unroll
        for (int p = 0; p < 8; ++p) {
            STAGE8(it * 8 + p + 6);
            const int d  = p >> 2;
            const int mh = p & 1, kh = (p >> 1) & 1;
            short8 af[4], bfr[4];
#pragma unroll
            for (int f = 0; f < 4; ++f) {
                const int row = wr * 128 + (mh * 4 + f) * 16 + fr;
                const int ch = lg ^ ((row >> 1) & 3);
                af[f] = *(const short8*)(&L[d][kh * 2][row * 32 + ch * 8]);
            }
#pragma unroll
            for (int g = 0; g < 4; ++g) {
                const int row = wc * 64 + g * 16 + fr;
                const int ch = lg ^ ((row >> 1) & 3);
                bfr[g] = *(const short8*)(&L[d][kh * 2 + 1][row * 32 + ch * 8]);
            }
            __builtin_amdgcn_s_barrier();
            __builtin_amdgcn_s_setprio(1);
#pragma unroll
            for (int f = 0; f < 4; ++f)
#pragma unroll
                for (int g = 0; g < 4; ++g)
                    acc[mh * 4 + f][g] = __builtin_amdgcn_mfma_f32_16x16x32_bf16(
                        af[f], bfr[g], acc[mh * 4 + f][g], 0, 0, 0);
            __builtin_amdgcn_s_setprio(0);
            if (p == 3 || p == 7) {
                asm volatile("s_waitcnt vmcnt(4)" ::: "memory");
                __builtin_amdgcn_sched_barrier(0);
            }
            __builtin_amdgcn_s_barrier();
        }
    }

#pragma unroll
    for (int mi = 0; mi < 8; ++mi) {
#pragma unroll
        for (int g = 0; g < 4; ++g) {
            const int col = bcol + wc * 64 + g * 16 + fr;
            const float bv = bias[col];
#pragma unroll
            for (int r = 0; r < 4; ++r) {
                const int row = brow + wr * 128 + mi * 16 + lg * 4 + r;
                const float v = fmaxf(acc[mi][g][r] + bv, 0.f);
                C[(size_t)row * N + col] = f2bf(v);
            }
        }
    }
#undef STAGE8
}

// ---------------------------------------------------------------------------
// LN1: bf16 in -> bf16 out (x = LN(preX))
// ---------------------------------------------------------------------------
__global__ __launch_bounds__(256) void ln_mid(
    const ushort_t* __restrict__ in, const float* __restrict__ g,
    const float* __restrict__ b, ushort_t* __restrict__ out)
{
    const int row = blockIdx.x;
    const int t = threadIdx.x;
    const uint2 u = ((const uint2*)(in + (size_t)row * EE))[t];
    float x[4];
    x[0] = bf2f(u.x & 0xffff); x[1] = bf2f(u.x >> 16);
    x[2] = bf2f(u.y & 0xffff); x[3] = bf2f(u.y >> 16);

    float s = 0.f, ss = 0.f;
#pragma unroll
    for (int i = 0; i < 4; ++i) { s += x[i]; ss += x[i] * x[i]; }
#pragma unroll
    for (int o = 1; o < 64; o <<= 1) {
        s  += __shfl_xor(s, o, 64);
        ss += __shfl_xor(ss, o, 64);
    }
    __shared__ float sm[8];
    const int wid = t >> 6;
    if ((t & 63) == 0) { sm[wid * 2] = s; sm[wid * 2 + 1] = ss; }
    __syncthreads();
    const float stot  = sm[0] + sm[2] + sm[4] + sm[6];
    const float sstot = sm[1] + sm[3] + sm[5] + sm[7];
    const float mu  = stot * (1.f / EE);
    const float inv = rsqrtf(sstot * (1.f / EE) - mu * mu + LN_EPS);

    const float4 gg = ((const float4*)g)[t];
    const float4 bb = ((const float4*)b)[t];
    uint2 pk;
    pk.x = f2bf((x[0] - mu) * inv * gg.x + bb.x) |
           ((unsigned)f2bf((x[1] - mu) * inv * gg.y + bb.y) << 16);
    pk.y = f2bf((x[2] - mu) * inv * gg.z + bb.z) |
           ((unsigned)f2bf((x[3] - mu) * inv * gg.w + bb.w) << 16);
    ((uint2*)(out + (size_t)row * EE))[t] = pk;
}

// ---------------------------------------------------------------------------
// LN2: out = LN(y0 + y1 + b2 + x), y0/y1/x bf16, out f32.
// ---------------------------------------------------------------------------
__global__ __launch_bounds__(256) void ln_out(
    const ushort_t* __restrict__ y0, const ushort_t* __restrict__ y1,
    const ushort_t* __restrict__ xb, const float* __restrict__ b2,
    const float* __restrict__ g, const float* __restrict__ be,
    float* __restrict__ out)
{
    const int row = blockIdx.x;
    const int t = threadIdx.x;
    const size_t off = (size_t)row * EE;
    const uint2 a = ((const uint2*)(y0 + off))[t];
    const uint2 b = ((const uint2*)(y1 + off))[t];
    const uint2 c = ((const uint2*)(xb + off))[t];
    const float4 bb2 = ((const float4*)b2)[t];
    float x[4];
    x[0] = bf2f(a.x & 0xffff) + bf2f(b.x & 0xffff) + bf2f(c.x & 0xffff) + bb2.x;
    x[1] = bf2f(a.x >> 16)    + bf2f(b.x >> 16)    + bf2f(c.x >> 16)    + bb2.y;
    x[2] = bf2f(a.y & 0xffff) + bf2f(b.y & 0xffff) + bf2f(c.y & 0xffff) + bb2.z;
    x[3] = bf2f(a.y >> 16)    + bf2f(b.y >> 16)    + bf2f(c.y >> 16)    + bb2.w;

    float s = 0.f, ss = 0.f;
#pragma unroll
    for (int i = 0; i < 4; ++i) { s += x[i]; ss += x[i] * x[i]; }
#pragma unroll
    for (int o = 1; o < 64; o <<= 1) {
        s  += __shfl_xor(s, o, 64);
        ss += __shfl_xor(ss, o, 64);
    }
    __shared__ float sm[8];
    const int wid = t >> 6;
    if ((t & 63) == 0) { sm[wid * 2] = s; sm[wid * 2 + 1] = ss; }
    __syncthreads();
    const float stot  = sm[0] + sm[2] + sm[4] + sm[6];
    const float sstot = sm[1] + sm[3] + sm[5] + sm[7];
    const float mu  = stot * (1.f / EE);
    const float inv = rsqrtf(sstot * (1.f / EE) - mu * mu + LN_EPS);

    const float4 gg = ((const float4*)g)[t];
    const float4 bb = ((const float4*)be)[t];
    float4 o;
    o.x = (x[0] - mu) * inv * gg.x + bb.x;
    o.y = (x[1] - mu) * inv * gg.y + bb.y;
    o.z = (x[2] - mu) * inv * gg.z + bb.z;
    o.w = (x[3] - mu) * inv * gg.w + bb.w;
    ((float4*)(out + off))[t] = o;
}

// ---------------------------------------------------------------------------
extern "C" void kernel_launch(void* const* d_in, const int* in_sizes, int n_in,
                              void* d_out, int out_size, void* d_ws, size_t ws_size,
                              hipStream_t stream) {
    (void)in_sizes; (void)n_in; (void)out_size; (void)ws_size;
    const float* value = (const float*)d_in[0];
    const float* key   = (const float*)d_in[1];
    const float* query = (const float*)d_in[2];
    const float* w_out = (const float*)d_in[3];
    const float* b_out = (const float*)d_in[4];
    const float* w1    = (const float*)d_in[5];
    const float* b1    = (const float*)d_in[6];
    const float* w2    = (const float*)d_in[7];
    const float* b2    = (const float*)d_in[8];
    const float* g1    = (const float*)d_in[9];
    const float* be1   = (const float*)d_in[10];
    const float* g2    = (const float*)d_in[11];
    const float* be2   = (const float*)d_in[12];
    float* out = (float*)d_out;

    const int M = NB * LL;  // 4096
    char* base = (char*)d_ws;
    ushort_t* attn_bf = (ushort_t*)(base);                      //  8 MB
    ushort_t* x_bf    = (ushort_t*)(base + (8ull  << 20));      //  8 MB
    char*     hregion = base + (16ull << 20);                   // 32 MB
    ushort_t* h_bf    = (ushort_t*)hregion;                     //  (post-attn)
    ushort_t* Kh      = (ushort_t*)(hregion);                   //  8 MB (pre-attn)
    ushort_t* Vt      = (ushort_t*)(hregion + (8ull  << 20));   //  8 MB
    ushort_t* preX_bf = (ushort_t*)(base + (48ull << 20));      //  8 MB
    ushort_t* y01     = (ushort_t*)(base + (56ull << 20));      // 16 MB (2 partials)
    ushort_t* w0T     = (ushort_t*)(base + (72ull << 20));      //  2 MB
    ushort_t* w1T     = (ushort_t*)(base + (74ull << 20));      //  8 MB
    ushort_t* w2T     = (ushort_t*)(base + (82ull << 20));      //  8 MB (ends 90)

    tcvt<<<dim3(EE / 32, EE / 32), 256, 0, stream>>>(w_out, w0T, EE, EE);
    tcvt<<<dim3(FFD / 32, EE / 32), 256, 0, stream>>>(w1, w1T, EE, FFD);
    tcvt<<<dim3(EE / 32, FFD / 32), 256, 0, stream>>>(w2, w2T, FFD, EE);

    k_cvt<<<NB * HH * LL / 32, 256, 0, stream>>>(key, Kh);
    v_cvt_t<<<dim3(LL / 64, HH, NB), 256, 0, stream>>>(value, Vt);

    attn_mfma<<<dim3(NB * HH * LL / 64), 256, 0, stream>>>(query, Kh, Vt,
                                                           attn_bf);

    // proj: [4096,1024] = attn_bf @ w_outT + b_out + query -> bf16 preX
    mfma_gemm<128, 64, false, true, true, true, 1>
        <<<dim3(EE / 64, M / 128), 256, 0, stream>>>(attn_bf, w0T, b_out, query,
                                                     preX_bf, M, EE, EE);
    ln_mid<<<M, 256, 0, stream>>>(preX_bf, g1, be1, x_bf);

    // ffn1: [4096,4096] = relu(x_bf @ w1T + b1), bf16 out (8-phase, 256 blocks)
    gemm8p<<<dim3(FFD / 256, M / 256), 512, 0, stream>>>(x_bf, w1T, b1, h_bf,
                                                         M, FFD, EE);
    // ffn2: split-K=2 -> two bf16 partials (no bias/res; LN2 fuses them)
    mfma_gemm<128, 64, false, false, true, false, 2>
        <<<dim3(EE / 64, M / 128, 2), 256, 0, stream>>>(h_bf, w2T, nullptr,
                                                        nullptr, y01, M, EE, FFD);
    ln_out<<<M, 256, 0, stream>>>(y01, y01 + (size_t)M * EE, x_bf, b2, g2, be2,
                                  out);
}

// Round 11
// 189.748 us; speedup vs baseline: 1.2139x; 1.1148x over previous
//
#include <hip/hip_runtime.h>
#include <hip/hip_bf16.h>

#define NB 2
#define LL 2048
#define EE 1024
#define HH 16
#define HDD 64
#define FFD 4096

typedef unsigned short ushort_t;
typedef __attribute__((ext_vector_type(8))) short short8;
typedef __attribute__((ext_vector_type(4))) float f32x4;

constexpr float LN_EPS = 1e-5f;
constexpr float QSCALE = 0.03125f * 1.44269504088896340736f;  // 1/32 * log2(e)

__device__ inline ushort_t f2bf(float f) {
    union { __hip_bfloat16 b; ushort_t u; } v;
    v.b = __float2bfloat16(f);
    return v.u;
}
__device__ inline float bf2f(unsigned us) {
    union { unsigned u; float f; } v; v.u = us << 16; return v.f;
}
// pack trunc-bf16(lo) | trunc-bf16(hi)<<16 in ONE v_perm_b32
__device__ inline unsigned pk_hi16(float lo, float hi) {
    const unsigned sel = 0x07060302u;
    unsigned r;
    asm("v_perm_b32 %0, %1, %2, %3" : "=v"(r) : "v"(hi), "v"(lo), "s"(sel));
    return r;
}

__device__ inline void gload16(const void* g, void* lds) {
    __builtin_amdgcn_global_load_lds(
        (const __attribute__((address_space(1))) void*)g,
        (__attribute__((address_space(3))) void*)lds, 16, 0, 0);
}

// ---------------------------------------------------------------------------
// K convert: [N,L,H,D] f32 -> [N,H,L,D] bf16.
// ---------------------------------------------------------------------------
__global__ __launch_bounds__(256) void k_cvt(
    const float* __restrict__ in, ushort_t* __restrict__ out)
{
    const int t = threadIdx.x;
    const int g = blockIdx.x * 32 + (t >> 3);          // (n*H+h)*L + l
    const int n = g >> 15, h = (g >> 11) & 15, l2 = g & 2047;
    const int d0 = (t & 7) * 8;
    const float* src = in + ((size_t)(n * LL + l2) * HH + h) * HDD + d0;
    const float4 a = *(const float4*)src;
    const float4 b = *(const float4*)(src + 4);
    uint4 pk;
    pk.x = f2bf(a.x) | ((unsigned)f2bf(a.y) << 16);
    pk.y = f2bf(a.z) | ((unsigned)f2bf(a.w) << 16);
    pk.z = f2bf(b.x) | ((unsigned)f2bf(b.y) << 16);
    pk.w = f2bf(b.z) | ((unsigned)f2bf(b.w) << 16);
    *(uint4*)(out + (size_t)g * HDD + d0) = pk;
}

// ---------------------------------------------------------------------------
// V convert+transpose: [N,L,H,D] f32 -> [N,H,D,L] bf16, kv-permuted columns:
//   phys(c') = ((c'>>5)*2 + ((c'>>2)&1))*16 + ((c'>>3)&3)*4 + (c'&3)
// ---------------------------------------------------------------------------
__global__ __launch_bounds__(256) void v_cvt_t(
    const float* __restrict__ in, ushort_t* __restrict__ out)
{
    __shared__ float T[64][68];
    const int lb = blockIdx.x, h = blockIdx.y, n = blockIdx.z;
    const int t = threadIdx.x;
    const int l0 = lb * 64;
    {
        const int r = t >> 2, c0 = (t & 3) * 16;
        const float* src = in + ((size_t)(n * LL + l0 + r) * HH + h) * HDD + c0;
#pragma unroll
        for (int i = 0; i < 4; ++i)
            *(float4*)&T[r][c0 + 4 * i] = *(const float4*)(src + 4 * i);
    }
    __syncthreads();
    {
        const int d = t >> 2, tq = t & 3;
        unsigned u[8];
#pragma unroll
        for (int k = 0; k < 8; ++k) {
            const int c0 = tq * 16 + 2 * k, c1 = c0 + 1;
            const int p0 = (((c0 >> 5) * 2 + ((c0 >> 2) & 1)) << 4) +
                           (((c0 >> 3) & 3) << 2) + (c0 & 3);
            const int p1 = (((c1 >> 5) * 2 + ((c1 >> 2) & 1)) << 4) +
                           (((c1 >> 3) & 3) << 2) + (c1 & 3);
            u[k] = f2bf(T[p0][d]) | ((unsigned)f2bf(T[p1][d]) << 16);
        }
        ushort_t* dst = out + ((size_t)(n * HH + h) * HDD + d) * LL + l0 + tq * 16;
        uint4 q0; q0.x = u[0]; q0.y = u[1]; q0.z = u[2]; q0.w = u[3];
        uint4 q1; q1.x = u[4]; q1.y = u[5]; q1.z = u[6]; q1.w = u[7];
        *(uint4*)(dst)     = q0;
        *(uint4*)(dst + 8) = q1;
    }
}

// ---------------------------------------------------------------------------
// MFMA flash attention, swapped QK^T, P in registers (v_perm trunc pack),
// native v_exp softmax, row-sum via MFMA ones-column, counted-vmcnt dbuf,
// XCD-bijective mapping. Block = (n,h,64 q), 4 waves x 16 q.
// ---------------------------------------------------------------------------
__global__ __launch_bounds__(256) void attn_mfma(
    const float* __restrict__ Qf,     // [N,L,H,D] f32 (raw query)
    const ushort_t* __restrict__ Kh,  // [N,H,L,D] bf16
    const ushort_t* __restrict__ Vt,  // [N,H,D,L] bf16 kv-permuted
    ushort_t* __restrict__ O)         // [N,L,E] bf16
{
    const int s = blockIdx.x;          // grid = 1024
    const int xcd = s & 7, seq = s >> 3;
    const int qb = seq & 31, tt = seq >> 5;
    const int h = ((tt & 1) << 3) | xcd;
    const int n = tt >> 1;

    const int t = threadIdx.x, w = t >> 6, l = t & 63;
    const int lr = l & 15, lg = l >> 4;

    __shared__ __align__(16) ushort_t Ks[2][64 * 64];
    __shared__ __align__(16) ushort_t Vs[2][64 * 64];

    const size_t hbase = ((size_t)n * HH + h) * LL * HDD;
    const size_t vbase = ((size_t)n * HH + h) * HDD * LL;
    const int q0 = qb * 64 + w * 16;

    short8 bq[2];
#pragma unroll
    for (int ks = 0; ks < 2; ++ks) {
        const float* qsrc = Qf + ((size_t)(n * LL + q0 + lr) * HH + h) * HDD
                               + ks * 32 + lg * 8;
        const float4 a = *(const float4*)qsrc;
        const float4 b = *(const float4*)(qsrc + 4);
        union { short8 s8; unsigned u[4]; } pk;
        pk.u[0] = f2bf(a.x * QSCALE) | ((unsigned)f2bf(a.y * QSCALE) << 16);
        pk.u[1] = f2bf(a.z * QSCALE) | ((unsigned)f2bf(a.w * QSCALE) << 16);
        pk.u[2] = f2bf(b.x * QSCALE) | ((unsigned)f2bf(b.y * QSCALE) << 16);
        pk.u[3] = f2bf(b.z * QSCALE) | ((unsigned)f2bf(b.w * QSCALE) << 16);
        bq[ks] = pk.s8;
    }

    union { short8 s8; ushort_t u[8]; } one_u;
#pragma unroll
    for (int i = 0; i < 8; ++i) one_u.u[i] = 0x3F80;
    const short8 ones = one_u.s8;

    f32x4 acco[4];
#pragma unroll
    for (int dn = 0; dn < 4; ++dn) {
        f32x4 z = {0.f, 0.f, 0.f, 0.f};
        acco[dn] = z;
    }
    f32x4 accp = {0.f, 0.f, 0.f, 0.f};

    const int id0 = w * 2;
#define STAGE(buf, kt)                                                         \
    {                                                                          \
        _Pragma("unroll")                                                      \
        for (int j = 0; j < 2; ++j) {                                          \
            const int id = (id0 + j) * 64 + l;                                 \
            const int r = id >> 3, c = id & 7;                                 \
            const int cs = c ^ (r & 7);                                        \
            gload16(Kh + hbase + (size_t)((kt) * 64 + r) * HDD + cs * 8,       \
                    (void*)(Ks[buf] + (id0 + j) * 512));                       \
            gload16(Vt + vbase + (size_t)r * LL + (kt) * 64 + cs * 8,          \
                    (void*)(Vs[buf] + (id0 + j) * 512));                       \
        }                                                                      \
    }

    constexpr int NT = LL / 64;
    STAGE(0, 0);
    STAGE(1, 1);
    asm volatile("s_waitcnt vmcnt(4)" ::: "memory");
    __builtin_amdgcn_sched_barrier(0);
    __builtin_amdgcn_s_barrier();

    const f32x4 z4 = {0.f, 0.f, 0.f, 0.f};

    for (int kt = 0; kt < NT; ++kt) {
        const int buf = kt & 1;

        // ---- S^T = K Q^T ----
        f32x4 accs[4];
        __builtin_amdgcn_s_setprio(1);
        {
            short8 ak[4];
#pragma unroll
            for (int nk = 0; nk < 4; ++nk) {
                const int row = nk * 16 + lr;
                ak[nk] = *(const short8*)(
                    Ks[buf] + row * 64 + ((lg) ^ (row & 7)) * 8);
            }
#pragma unroll
            for (int nk = 0; nk < 4; ++nk)
                accs[nk] = __builtin_amdgcn_mfma_f32_16x16x32_bf16(
                    ak[nk], bq[0], z4, 0, 0, 0);
#pragma unroll
            for (int nk = 0; nk < 4; ++nk) {
                const int row = nk * 16 + lr;
                ak[nk] = *(const short8*)(
                    Ks[buf] + row * 64 + ((4 | lg) ^ (row & 7)) * 8);
            }
#pragma unroll
            for (int nk = 0; nk < 4; ++nk)
                accs[nk] = __builtin_amdgcn_mfma_f32_16x16x32_bf16(
                    ak[nk], bq[1], accs[nk], 0, 0, 0);
        }
        __builtin_amdgcn_s_setprio(0);

        // ---- P = 2^S, v_perm trunc pack (self-normalizing) ----
        float p[4][4];
#pragma unroll
        for (int nk = 0; nk < 4; ++nk)
#pragma unroll
            for (int r = 0; r < 4; ++r)
                p[nk][r] = __builtin_amdgcn_exp2f(accs[nk][r]);
        short8 pa[2];
#pragma unroll
        for (int ks = 0; ks < 2; ++ks) {
            union { short8 s8; unsigned u[4]; } pk;
            pk.u[0] = pk_hi16(p[2*ks][0],   p[2*ks][1]);
            pk.u[1] = pk_hi16(p[2*ks][2],   p[2*ks][3]);
            pk.u[2] = pk_hi16(p[2*ks+1][0], p[2*ks+1][1]);
            pk.u[3] = pk_hi16(p[2*ks+1][2], p[2*ks+1][3]);
            pa[ks] = pk.s8;
        }

        // ---- O += P V ; row-sum += P @ ones ----
        __builtin_amdgcn_s_setprio(1);
#pragma unroll
        for (int ks = 0; ks < 2; ++ks) {
            short8 bv[4];
#pragma unroll
            for (int dn = 0; dn < 4; ++dn) {
                const int row = dn * 16 + lr;
                bv[dn] = *(const short8*)(
                    Vs[buf] + row * 64 + (((ks << 2) | lg) ^ (row & 7)) * 8);
            }
            accp = __builtin_amdgcn_mfma_f32_16x16x32_bf16(pa[ks], ones, accp,
                                                           0, 0, 0);
#pragma unroll
            for (int dn = 0; dn < 4; ++dn)
                acco[dn] = __builtin_amdgcn_mfma_f32_16x16x32_bf16(
                    pa[ks], bv[dn], acco[dn], 0, 0, 0);
        }
        __builtin_amdgcn_s_setprio(0);

        // ---- counted pipeline; UNCLAMPED kt+2 (affine addr; dead loads
        //      land in dead buffer, <=16KB past head slice, in-buffer) ----
        __builtin_amdgcn_s_barrier();
        STAGE(buf, kt + 2);
        asm volatile("s_waitcnt vmcnt(4)" ::: "memory");
        __builtin_amdgcn_sched_barrier(0);
        __builtin_amdgcn_s_barrier();
    }

#pragma unroll
    for (int r = 0; r < 4; ++r) {
        const float invl = 1.f / accp[r];
        const int qq = q0 + lg * 4 + r;
        ushort_t* dst = O + (size_t)(n * LL + qq) * EE + h * HDD + lr;
#pragma unroll
        for (int dn = 0; dn < 4; ++dn)
            dst[dn * 16] = f2bf(acco[dn][r] * invl);
    }
#undef STAGE
}

// ---------------------------------------------------------------------------
// Transpose+convert: in f32 [K][N] -> out bf16 [N][K]
// ---------------------------------------------------------------------------
__global__ __launch_bounds__(256) void tcvt(
    const float* __restrict__ in, ushort_t* __restrict__ out, int K, int N)
{
    __shared__ float T[32][36];
    const int n0 = blockIdx.x * 32, k0 = blockIdx.y * 32;
    const int r = threadIdx.x >> 3, c4 = (threadIdx.x & 7) * 4;
    const float4 v = *(const float4*)(in + (size_t)(k0 + r) * N + n0 + c4);
    T[r][c4] = v.x; T[r][c4 + 1] = v.y; T[r][c4 + 2] = v.z; T[r][c4 + 3] = v.w;
    __syncthreads();
    const unsigned a = f2bf(T[c4][r])     | ((unsigned)f2bf(T[c4 + 1][r]) << 16);
    const unsigned b = f2bf(T[c4 + 2][r]) | ((unsigned)f2bf(T[c4 + 3][r]) << 16);
    uint2 pk; pk.x = a; pk.y = b;
    *(uint2*)(out + (size_t)(n0 + r) * K + k0 + c4) = pk;
}

// ---------------------------------------------------------------------------
// 8-phase 256x256 bf16 MFMA GEMM (ffn1): C = relu(A @ Bt^T + bias), bf16 out.
// ---------------------------------------------------------------------------
__global__ __launch_bounds__(512, 2) void gemm8p(
    const ushort_t* __restrict__ A, const ushort_t* __restrict__ Bt,
    const float* __restrict__ bias, ushort_t* __restrict__ C,
    int M, int N, int K)
{
    __shared__ __align__(16) ushort_t L[2][4][256 * 32];  // 128 KiB

    const int tid = threadIdx.x;
    const int w = tid >> 6, l = tid & 63;
    const int fr = l & 15, lg = l >> 4;
    const int wr = w >> 2, wc = w & 3;

    const int gx = gridDim.x;
    const int nwg = gx * gridDim.y;
    const int bid = blockIdx.y * gx + blockIdx.x;
    int tile = bid;
    if ((nwg & 7) == 0) tile = (bid & 7) * (nwg >> 3) + (bid >> 3);
    const int bx = tile % gx, by = tile / gx;
    const int brow = by * 256, bcol = bx * 256;

    const int NT = K >> 6;
    const int UMAX = NT << 2;

#define STAGE8(u)                                                              \
    if ((u) < UMAX) {                                                          \
        const int tt = (u) >> 2, slot = (u) & 3;                               \
        const int op = slot & 1, kh = slot >> 1;                               \
        const ushort_t* sp = op ? Bt : A;                                      \
        const int rb = op ? bcol : brow;                                       \
        ushort_t* db = (ushort_t*)L[tt & 1][slot];                             \
        _Pragma("unroll")                                                      \
        for (int j = 0; j < 2; ++j) {                                          \
            const int id = j * 512 + tid;                                      \
            const int row = id >> 2, c = id & 3;                               \
            const int cs = c ^ ((row >> 1) & 3);                               \
            gload16(sp + (size_t)(rb + row) * K + tt * 64 + kh * 32 + cs * 8,  \
                    (void*)(db + id * 8));                                     \
        }                                                                      \
    }

    f32x4 acc[8][4];
#pragma unroll
    for (int i = 0; i < 8; ++i)
#pragma unroll
        for (int g = 0; g < 4; ++g) { f32x4 zz = {0.f,0.f,0.f,0.f}; acc[i][g] = zz; }

#pragma unroll
    for (int u = 0; u < 6; ++u) STAGE8(u);
    asm volatile("s_waitcnt vmcnt(4)" ::: "memory");
    __builtin_amdgcn_sched_barrier(0);
    __builtin_amdgcn_s_barrier();

    const int iters = NT >> 1;
    for (int it = 0; it < iters; ++it) {
#pragma unroll
        for (int p = 0; p < 8; ++p) {
            STAGE8(it * 8 + p + 6);
            const int d  = p >> 2;
            const int mh = p & 1, kh = (p >> 1) & 1;
            short8 af[4], bfr[4];
#pragma unroll
            for (int f = 0; f < 4; ++f) {
                const int row = wr * 128 + (mh * 4 + f) * 16 + fr;
                const int ch = lg ^ ((row >> 1) & 3);
                af[f] = *(const short8*)(&L[d][kh * 2][row * 32 + ch * 8]);
            }
#pragma unroll
            for (int g = 0; g < 4; ++g) {
                const int row = wc * 64 + g * 16 + fr;
                const int ch = lg ^ ((row >> 1) & 3);
                bfr[g] = *(const short8*)(&L[d][kh * 2 + 1][row * 32 + ch * 8]);
            }
            __builtin_amdgcn_s_barrier();
            __builtin_amdgcn_s_setprio(1);
#pragma unroll
            for (int f = 0; f < 4; ++f)
#pragma unroll
                for (int g = 0; g < 4; ++g)
                    acc[mh * 4 + f][g] = __builtin_amdgcn_mfma_f32_16x16x32_bf16(
                        af[f], bfr[g], acc[mh * 4 + f][g], 0, 0, 0);
            __builtin_amdgcn_s_setprio(0);
            if (p == 3 || p == 7) {
                asm volatile("s_waitcnt vmcnt(4)" ::: "memory");
                __builtin_amdgcn_sched_barrier(0);
            }
            __builtin_amdgcn_s_barrier();
        }
    }

#pragma unroll
    for (int mi = 0; mi < 8; ++mi) {
#pragma unroll
        for (int g = 0; g < 4; ++g) {
            const int col = bcol + wc * 64 + g * 16 + fr;
            const float bv = bias[col];
#pragma unroll
            for (int r = 0; r < 4; ++r) {
                const int row = brow + wr * 128 + mi * 16 + lg * 4 + r;
                const float v = fmaxf(acc[mi][g][r] + bv, 0.f);
                C[(size_t)row * N + col] = f2bf(v);
            }
        }
    }
#undef STAGE8
}

// ---------------------------------------------------------------------------
// 8-phase 256x128 bf16 MFMA GEMM, split-K partials (proj & ffn2).
// LDS 96KB: per dbuf {A_k0 16K | B_k0 8K | A_k1 16K | B_k1 8K}.
// Loads/thread: A-slot 2, B-slot 1 -> tile = 6; counted vmcnt(3).
// ---------------------------------------------------------------------------
#define SOFF(slot) ((slot) == 0 ? 0 : (slot) == 1 ? 8192 : (slot) == 2 ? 12288 : 20480)

template <int KSPLIT>
__global__ __launch_bounds__(512, 2) void gemm8p_n128(
    const ushort_t* __restrict__ A, const ushort_t* __restrict__ Bt,
    ushort_t* __restrict__ C, int M, int N, int K)
{
    __shared__ __align__(16) ushort_t L[2][24576];  // 96 KiB

    const int tid = threadIdx.x;
    const int w = tid >> 6, l = tid & 63;
    const int fr = l & 15, lg = l >> 4;
    const int wr = w >> 2, wc = w & 3;

    const int z = blockIdx.z;
    const int Keff = K / KSPLIT;
    const int kb = z * Keff;

    const int gx = gridDim.x;
    const int nwg = gx * gridDim.y;
    const int bid = blockIdx.y * gx + blockIdx.x;
    int tile = bid;
    if ((nwg & 7) == 0) tile = (bid & 7) * (nwg >> 3) + (bid >> 3);
    const int bx = tile % gx, by = tile / gx;
    const int brow = by * 256, bcol = bx * 128;

    const int NT = Keff >> 6;
    const int UMAX = NT << 2;

#define STG(u)                                                                 \
    if ((u) < UMAX) {                                                          \
        const int tt = (u) >> 2, slot = (u) & 3;                               \
        const int op = slot & 1, kh = slot >> 1;                               \
        const ushort_t* sp = op ? Bt : A;                                      \
        const int rb = op ? bcol : brow;                                       \
        ushort_t* db = (ushort_t*)L[tt & 1] + SOFF(slot);                      \
        const int nld = op ? 1 : 2;                                            \
        _Pragma("unroll")                                                      \
        for (int j = 0; j < nld; ++j) {                                        \
            const int id = j * 512 + tid;                                      \
            const int row = id >> 2, c = id & 3;                               \
            const int cs = c ^ ((row >> 1) & 3);                               \
            gload16(sp + (size_t)(rb + row) * K + kb + tt * 64 + kh * 32 + cs * 8, \
                    (void*)(db + id * 8));                                     \
        }                                                                      \
    }

    f32x4 acc[8][2];
#pragma unroll
    for (int i = 0; i < 8; ++i)
#pragma unroll
        for (int g = 0; g < 2; ++g) { f32x4 zz = {0.f,0.f,0.f,0.f}; acc[i][g] = zz; }

#pragma unroll
    for (int u = 0; u < 6; ++u) STG(u);
    asm volatile("s_waitcnt vmcnt(3)" ::: "memory");
    __builtin_amdgcn_sched_barrier(0);
    __builtin_amdgcn_s_barrier();

    const int iters = NT >> 1;
    for (int it = 0; it < iters; ++it) {
#pragma unroll
        for (int p = 0; p < 8; ++p) {
            STG(it * 8 + p + 6);
            const int d  = p >> 2;
            const int mh = p & 1, kh = (p >> 1) & 1;
            short8 af[4], bfr[2];
#pragma unroll
            for (int f = 0; f < 4; ++f) {
                const int row = wr * 128 + (mh * 4 + f) * 16 + fr;
                const int ch = lg ^ ((row >> 1) & 3);
                af[f] = *(const short8*)(&L[d][SOFF(kh * 2) + row * 32 + ch * 8]);
            }
#pragma unroll
            for (int g = 0; g < 2; ++g) {
                const int row = wc * 32 + g * 16 + fr;
                const int ch = lg ^ ((row >> 1) & 3);
                bfr[g] = *(const short8*)(&L[d][SOFF(kh * 2 + 1) + row * 32 + ch * 8]);
            }
            __builtin_amdgcn_s_barrier();
            __builtin_amdgcn_s_setprio(1);
#pragma unroll
            for (int f = 0; f < 4; ++f)
#pragma unroll
                for (int g = 0; g < 2; ++g)
                    acc[mh * 4 + f][g] = __builtin_amdgcn_mfma_f32_16x16x32_bf16(
                        af[f], bfr[g], acc[mh * 4 + f][g], 0, 0, 0);
            __builtin_amdgcn_s_setprio(0);
            if (p == 3 || p == 7) {
                asm volatile("s_waitcnt vmcnt(3)" ::: "memory");
                __builtin_amdgcn_sched_barrier(0);
            }
            __builtin_amdgcn_s_barrier();
        }
    }

    ushort_t* Cb = C + (size_t)z * M * N;
#pragma unroll
    for (int mi = 0; mi < 8; ++mi) {
#pragma unroll
        for (int g = 0; g < 2; ++g) {
            const int col = bcol + wc * 32 + g * 16 + fr;
#pragma unroll
            for (int r = 0; r < 4; ++r) {
                const int row = brow + wr * 128 + mi * 16 + lg * 4 + r;
                Cb[(size_t)row * N + col] = f2bf(acc[mi][g][r]);
            }
        }
    }
#undef STG
}

// ---------------------------------------------------------------------------
// LN1: x = LN(p0 + p1 + b_out + query), p bf16 / query f32; bf16 out.
// ---------------------------------------------------------------------------
__global__ __launch_bounds__(256) void ln_mid(
    const ushort_t* __restrict__ y0, const ushort_t* __restrict__ y1,
    const float* __restrict__ qres, const float* __restrict__ b0,
    const float* __restrict__ g, const float* __restrict__ b,
    ushort_t* __restrict__ out)
{
    const int row = blockIdx.x;
    const int t = threadIdx.x;
    const size_t off = (size_t)row * EE;
    const uint2 a = ((const uint2*)(y0 + off))[t];
    const uint2 c = ((const uint2*)(y1 + off))[t];
    const float4 qq = ((const float4*)(qres + off))[t];
    const float4 b04 = ((const float4*)b0)[t];
    float x[4];
    x[0] = bf2f(a.x & 0xffff) + bf2f(c.x & 0xffff) + qq.x + b04.x;
    x[1] = bf2f(a.x >> 16)    + bf2f(c.x >> 16)    + qq.y + b04.y;
    x[2] = bf2f(a.y & 0xffff) + bf2f(c.y & 0xffff) + qq.z + b04.z;
    x[3] = bf2f(a.y >> 16)    + bf2f(c.y >> 16)    + qq.w + b04.w;

    float s = 0.f, ss = 0.f;
#pragma unroll
    for (int i = 0; i < 4; ++i) { s += x[i]; ss += x[i] * x[i]; }
#pragma unroll
    for (int o = 1; o < 64; o <<= 1) {
        s  += __shfl_xor(s, o, 64);
        ss += __shfl_xor(ss, o, 64);
    }
    __shared__ float sm[8];
    const int wid = t >> 6;
    if ((t & 63) == 0) { sm[wid * 2] = s; sm[wid * 2 + 1] = ss; }
    __syncthreads();
    const float stot  = sm[0] + sm[2] + sm[4] + sm[6];
    const float sstot = sm[1] + sm[3] + sm[5] + sm[7];
    const float mu  = stot * (1.f / EE);
    const float inv = rsqrtf(sstot * (1.f / EE) - mu * mu + LN_EPS);

    const float4 gg = ((const float4*)g)[t];
    const float4 bb = ((const float4*)b)[t];
    uint2 pk;
    pk.x = f2bf((x[0] - mu) * inv * gg.x + bb.x) |
           ((unsigned)f2bf((x[1] - mu) * inv * gg.y + bb.y) << 16);
    pk.y = f2bf((x[2] - mu) * inv * gg.z + bb.z) |
           ((unsigned)f2bf((x[3] - mu) * inv * gg.w + bb.w) << 16);
    ((uint2*)(out + off))[t] = pk;
}

// ---------------------------------------------------------------------------
// LN2: out = LN(y0 + y1 + b2 + x), all-bf16 inputs, f32 out.
// ---------------------------------------------------------------------------
__global__ __launch_bounds__(256) void ln_out(
    const ushort_t* __restrict__ y0, const ushort_t* __restrict__ y1,
    const ushort_t* __restrict__ xb, const float* __restrict__ b2,
    const float* __restrict__ g, const float* __restrict__ be,
    float* __restrict__ out)
{
    const int row = blockIdx.x;
    const int t = threadIdx.x;
    const size_t off = (size_t)row * EE;
    const uint2 a = ((const uint2*)(y0 + off))[t];
    const uint2 b = ((const uint2*)(y1 + off))[t];
    const uint2 c = ((const uint2*)(xb + off))[t];
    const float4 bb2 = ((const float4*)b2)[t];
    float x[4];
    x[0] = bf2f(a.x & 0xffff) + bf2f(b.x & 0xffff) + bf2f(c.x & 0xffff) + bb2.x;
    x[1] = bf2f(a.x >> 16)    + bf2f(b.x >> 16)    + bf2f(c.x >> 16)    + bb2.y;
    x[2] = bf2f(a.y & 0xffff) + bf2f(b.y & 0xffff) + bf2f(c.y & 0xffff) + bb2.z;
    x[3] = bf2f(a.y >> 16)    + bf2f(b.y >> 16)    + bf2f(c.y >> 16)    + bb2.w;

    float s = 0.f, ss = 0.f;
#pragma unroll
    for (int i = 0; i < 4; ++i) { s += x[i]; ss += x[i] * x[i]; }
#pragma unroll
    for (int o = 1; o < 64; o <<= 1) {
        s  += __shfl_xor(s, o, 64);
        ss += __shfl_xor(ss, o, 64);
    }
    __shared__ float sm[8];
    const int wid = t >> 6;
    if ((t & 63) == 0) { sm[wid * 2] = s; sm[wid * 2 + 1] = ss; }
    __syncthreads();
    const float stot  = sm[0] + sm[2] + sm[4] + sm[6];
    const float sstot = sm[1] + sm[3] + sm[5] + sm[7];
    const float mu  = stot * (1.f / EE);
    const float inv = rsqrtf(sstot * (1.f / EE) - mu * mu + LN_EPS);

    const float4 gg = ((const float4*)g)[t];
    const float4 bb = ((const float4*)be)[t];
    float4 o;
    o.x = (x[0] - mu) * inv * gg.x + bb.x;
    o.y = (x[1] - mu) * inv * gg.y + bb.y;
    o.z = (x[2] - mu) * inv * gg.z + bb.z;
    o.w = (x[3] - mu) * inv * gg.w + bb.w;
    ((float4*)(out + off))[t] = o;
}

// ---------------------------------------------------------------------------
extern "C" void kernel_launch(void* const* d_in, const int* in_sizes, int n_in,
                              void* d_out, int out_size, void* d_ws, size_t ws_size,
                              hipStream_t stream) {
    (void)in_sizes; (void)n_in; (void)out_size; (void)ws_size;
    const float* value = (const float*)d_in[0];
    const float* key   = (const float*)d_in[1];
    const float* query = (const float*)d_in[2];
    const float* w_out = (const float*)d_in[3];
    const float* b_out = (const float*)d_in[4];
    const float* w1    = (const float*)d_in[5];
    const float* b1    = (const float*)d_in[6];
    const float* w2    = (const float*)d_in[7];
    const float* b2    = (const float*)d_in[8];
    const float* g1    = (const float*)d_in[9];
    const float* be1   = (const float*)d_in[10];
    const float* g2    = (const float*)d_in[11];
    const float* be2   = (const float*)d_in[12];
    float* out = (float*)d_out;

    const int M = NB * LL;  // 4096
    char* base = (char*)d_ws;
    ushort_t* attn_bf = (ushort_t*)(base);                      //  8 MB
    ushort_t* x_bf    = (ushort_t*)(base + (8ull  << 20));      //  8 MB
    char*     hregion = base + (16ull << 20);                   // 32 MB
    ushort_t* h_bf    = (ushort_t*)hregion;                     //  (post-attn)
    ushort_t* Kh      = (ushort_t*)(hregion);                   //  8 MB (pre-attn)
    ushort_t* Vt      = (ushort_t*)(hregion + (8ull  << 20));   //  8 MB
    ushort_t* y01     = (ushort_t*)(base + (48ull << 20));      // 16 MB (2 partials)
    ushort_t* w0T     = (ushort_t*)(base + (64ull << 20));      //  2 MB
    ushort_t* w1T     = (ushort_t*)(base + (66ull << 20));      //  8 MB
    ushort_t* w2T     = (ushort_t*)(base + (74ull << 20));      //  8 MB (ends 82)

    tcvt<<<dim3(EE / 32, EE / 32), 256, 0, stream>>>(w_out, w0T, EE, EE);
    tcvt<<<dim3(FFD / 32, EE / 32), 256, 0, stream>>>(w1, w1T, EE, FFD);
    tcvt<<<dim3(EE / 32, FFD / 32), 256, 0, stream>>>(w2, w2T, FFD, EE);

    k_cvt<<<NB * HH * LL / 32, 256, 0, stream>>>(key, Kh);
    v_cvt_t<<<dim3(LL / 64, HH, NB), 256, 0, stream>>>(value, Vt);

    attn_mfma<<<dim3(NB * HH * LL / 64), 256, 0, stream>>>(query, Kh, Vt,
                                                           attn_bf);

    // proj: split-K=2 partials (8-phase 256x128), bias+residual fused in LN1
    gemm8p_n128<2><<<dim3(EE / 128, M / 256, 2), 512, 0, stream>>>(
        attn_bf, w0T, y01, M, EE, EE);
    ln_mid<<<M, 256, 0, stream>>>(y01, y01 + (size_t)M * EE, query, b_out,
                                  g1, be1, x_bf);

    // ffn1: [4096,4096] = relu(x_bf @ w1T + b1), bf16 out (8-phase 256x256)
    gemm8p<<<dim3(FFD / 256, M / 256), 512, 0, stream>>>(x_bf, w1T, b1, h_bf,
                                                         M, FFD, EE);
    // ffn2: split-K=2 partials (8-phase 256x128)
    gemm8p_n128<2><<<dim3(EE / 128, M / 256, 2), 512, 0, stream>>>(
        h_bf, w2T, y01, M, EE, FFD);
    ln_out<<<M, 256, 0, stream>>>(y01, y01 + (size_t)M * EE, x_bf, b2, g2, be2,
                                  out);
}

// Round 12
// 185.976 us; speedup vs baseline: 1.2385x; 1.0203x over previous
//
#include <hip/hip_runtime.h>
#include <hip/hip_bf16.h>

#define NB 2
#define LL 2048
#define EE 1024
#define HH 16
#define HDD 64
#define FFD 4096

typedef unsigned short ushort_t;
typedef __attribute__((ext_vector_type(8))) short short8;
typedef __attribute__((ext_vector_type(4))) float f32x4;

constexpr float LN_EPS = 1e-5f;
constexpr float QSCALE = 0.03125f * 1.44269504088896340736f;  // 1/32 * log2(e)

__device__ inline ushort_t f2bf(float f) {
    union { __hip_bfloat16 b; ushort_t u; } v;
    v.b = __float2bfloat16(f);
    return v.u;
}
__device__ inline float bf2f(unsigned us) {
    union { unsigned u; float f; } v; v.u = us << 16; return v.f;
}
// pack trunc-bf16(lo) | trunc-bf16(hi)<<16 in ONE v_perm_b32
__device__ inline unsigned pk_hi16(float lo, float hi) {
    const unsigned sel = 0x07060302u;
    unsigned r;
    asm("v_perm_b32 %0, %1, %2, %3" : "=v"(r) : "v"(hi), "v"(lo), "s"(sel));
    return r;
}

__device__ inline void gload16(const void* g, void* lds) {
    __builtin_amdgcn_global_load_lds(
        (const __attribute__((address_space(1))) void*)g,
        (__attribute__((address_space(3))) void*)lds, 16, 0, 0);
}

// ---------------------------------------------------------------------------
// K convert: [N,L,H,D] f32 -> [N,H,L,D] bf16.
// ---------------------------------------------------------------------------
__global__ __launch_bounds__(256) void k_cvt(
    const float* __restrict__ in, ushort_t* __restrict__ out)
{
    const int t = threadIdx.x;
    const int g = blockIdx.x * 32 + (t >> 3);          // (n*H+h)*L + l
    const int n = g >> 15, h = (g >> 11) & 15, l2 = g & 2047;
    const int d0 = (t & 7) * 8;
    const float* src = in + ((size_t)(n * LL + l2) * HH + h) * HDD + d0;
    const float4 a = *(const float4*)src;
    const float4 b = *(const float4*)(src + 4);
    uint4 pk;
    pk.x = f2bf(a.x) | ((unsigned)f2bf(a.y) << 16);
    pk.y = f2bf(a.z) | ((unsigned)f2bf(a.w) << 16);
    pk.z = f2bf(b.x) | ((unsigned)f2bf(b.y) << 16);
    pk.w = f2bf(b.z) | ((unsigned)f2bf(b.w) << 16);
    *(uint4*)(out + (size_t)g * HDD + d0) = pk;
}

// ---------------------------------------------------------------------------
// V convert+transpose: [N,L,H,D] f32 -> [N,H,D,L] bf16, kv-permuted columns:
//   phys(c') = ((c'>>5)*2 + ((c'>>2)&1))*16 + ((c'>>3)&3)*4 + (c'&3)
// ---------------------------------------------------------------------------
__global__ __launch_bounds__(256) void v_cvt_t(
    const float* __restrict__ in, ushort_t* __restrict__ out)
{
    __shared__ float T[64][68];
    const int lb = blockIdx.x, h = blockIdx.y, n = blockIdx.z;
    const int t = threadIdx.x;
    const int l0 = lb * 64;
    {
        const int r = t >> 2, c0 = (t & 3) * 16;
        const float* src = in + ((size_t)(n * LL + l0 + r) * HH + h) * HDD + c0;
#pragma unroll
        for (int i = 0; i < 4; ++i)
            *(float4*)&T[r][c0 + 4 * i] = *(const float4*)(src + 4 * i);
    }
    __syncthreads();
    {
        const int d = t >> 2, tq = t & 3;
        unsigned u[8];
#pragma unroll
        for (int k = 0; k < 8; ++k) {
            const int c0 = tq * 16 + 2 * k, c1 = c0 + 1;
            const int p0 = (((c0 >> 5) * 2 + ((c0 >> 2) & 1)) << 4) +
                           (((c0 >> 3) & 3) << 2) + (c0 & 3);
            const int p1 = (((c1 >> 5) * 2 + ((c1 >> 2) & 1)) << 4) +
                           (((c1 >> 3) & 3) << 2) + (c1 & 3);
            u[k] = f2bf(T[p0][d]) | ((unsigned)f2bf(T[p1][d]) << 16);
        }
        ushort_t* dst = out + ((size_t)(n * HH + h) * HDD + d) * LL + l0 + tq * 16;
        uint4 q0; q0.x = u[0]; q0.y = u[1]; q0.z = u[2]; q0.w = u[3];
        uint4 q1; q1.x = u[4]; q1.y = u[5]; q1.z = u[6]; q1.w = u[7];
        *(uint4*)(dst)     = q0;
        *(uint4*)(dst + 8) = q1;
    }
}

// ---------------------------------------------------------------------------
// MFMA flash attention, 2 q-tiles per wave (LDS-operand register blocking):
// each staged K/V fragment read once from LDS feeds 2 MFMAs (one per q-tile).
// Swapped QK^T, in-register P, native v_exp, ones-column row-sum, counted
// vmcnt dbuf, XCD-bijective mapping. Block = (n,h,128 q), 4 waves x 32 q.
// ---------------------------------------------------------------------------
__global__ __launch_bounds__(256) void attn_mfma(
    const float* __restrict__ Qf,     // [N,L,H,D] f32 (raw query)
    const ushort_t* __restrict__ Kh,  // [N,H,L,D] bf16
    const ushort_t* __restrict__ Vt,  // [N,H,D,L] bf16 kv-permuted
    ushort_t* __restrict__ O)         // [N,L,E] bf16
{
    const int s = blockIdx.x;          // grid = 512
    const int xcd = s & 7, seq = s >> 3;
    const int qb = seq & 15, tt = seq >> 4;
    const int h = ((tt & 1) << 3) | xcd;
    const int n = tt >> 1;

    const int t = threadIdx.x, w = t >> 6, l = t & 63;
    const int lr = l & 15, lg = l >> 4;

    __shared__ __align__(16) ushort_t Ks[2][64 * 64];
    __shared__ __align__(16) ushort_t Vs[2][64 * 64];

    const size_t hbase = ((size_t)n * HH + h) * LL * HDD;
    const size_t vbase = ((size_t)n * HH + h) * HDD * LL;
    const int q0 = qb * 128 + w * 32;   // wave owns 32 q-rows (2 MFMA tiles)

    // Q fragments (B-operand), converted+scaled in-kernel
    short8 bq[2][2];
#pragma unroll
    for (int mi = 0; mi < 2; ++mi)
#pragma unroll
        for (int ks = 0; ks < 2; ++ks) {
            const float* qsrc = Qf +
                ((size_t)(n * LL + q0 + mi * 16 + lr) * HH + h) * HDD
                + ks * 32 + lg * 8;
            const float4 a = *(const float4*)qsrc;
            const float4 b = *(const float4*)(qsrc + 4);
            union { short8 s8; unsigned u[4]; } pk;
            pk.u[0] = f2bf(a.x * QSCALE) | ((unsigned)f2bf(a.y * QSCALE) << 16);
            pk.u[1] = f2bf(a.z * QSCALE) | ((unsigned)f2bf(a.w * QSCALE) << 16);
            pk.u[2] = f2bf(b.x * QSCALE) | ((unsigned)f2bf(b.y * QSCALE) << 16);
            pk.u[3] = f2bf(b.z * QSCALE) | ((unsigned)f2bf(b.w * QSCALE) << 16);
            bq[mi][ks] = pk.s8;
        }

    union { short8 s8; ushort_t u[8]; } one_u;
#pragma unroll
    for (int i = 0; i < 8; ++i) one_u.u[i] = 0x3F80;
    const short8 ones = one_u.s8;

    f32x4 acco[2][4];
#pragma unroll
    for (int mi = 0; mi < 2; ++mi)
#pragma unroll
        for (int dn = 0; dn < 4; ++dn) {
            f32x4 z = {0.f, 0.f, 0.f, 0.f};
            acco[mi][dn] = z;
        }
    f32x4 accp[2];
    accp[0] = (f32x4){0.f, 0.f, 0.f, 0.f};
    accp[1] = (f32x4){0.f, 0.f, 0.f, 0.f};

    const int id0 = w * 2;
#define STAGE(buf, kt)                                                         \
    {                                                                          \
        _Pragma("unroll")                                                      \
        for (int j = 0; j < 2; ++j) {                                          \
            const int id = (id0 + j) * 64 + l;                                 \
            const int r = id >> 3, c = id & 7;                                 \
            const int cs = c ^ (r & 7);                                        \
            gload16(Kh + hbase + (size_t)((kt) * 64 + r) * HDD + cs * 8,       \
                    (void*)(Ks[buf] + (id0 + j) * 512));                       \
            gload16(Vt + vbase + (size_t)r * LL + (kt) * 64 + cs * 8,          \
                    (void*)(Vs[buf] + (id0 + j) * 512));                       \
        }                                                                      \
    }

    constexpr int NT = LL / 64;
    STAGE(0, 0);
    STAGE(1, 1);
    asm volatile("s_waitcnt vmcnt(4)" ::: "memory");
    __builtin_amdgcn_sched_barrier(0);
    __builtin_amdgcn_s_barrier();

    const f32x4 z4 = {0.f, 0.f, 0.f, 0.f};

    for (int kt = 0; kt < NT; ++kt) {
        const int buf = kt & 1;

        // ---- S^T = K Q^T : one ak read feeds both q-tiles ----
        f32x4 accs[2][4];
        __builtin_amdgcn_s_setprio(1);
        {
            short8 ak[4];
#pragma unroll
            for (int nk = 0; nk < 4; ++nk) {
                const int row = nk * 16 + lr;
                ak[nk] = *(const short8*)(
                    Ks[buf] + row * 64 + ((lg) ^ (row & 7)) * 8);
            }
#pragma unroll
            for (int nk = 0; nk < 4; ++nk) {
                accs[0][nk] = __builtin_amdgcn_mfma_f32_16x16x32_bf16(
                    ak[nk], bq[0][0], z4, 0, 0, 0);
                accs[1][nk] = __builtin_amdgcn_mfma_f32_16x16x32_bf16(
                    ak[nk], bq[1][0], z4, 0, 0, 0);
            }
#pragma unroll
            for (int nk = 0; nk < 4; ++nk) {
                const int row = nk * 16 + lr;
                ak[nk] = *(const short8*)(
                    Ks[buf] + row * 64 + ((4 | lg) ^ (row & 7)) * 8);
            }
#pragma unroll
            for (int nk = 0; nk < 4; ++nk) {
                accs[0][nk] = __builtin_amdgcn_mfma_f32_16x16x32_bf16(
                    ak[nk], bq[0][1], accs[0][nk], 0, 0, 0);
                accs[1][nk] = __builtin_amdgcn_mfma_f32_16x16x32_bf16(
                    ak[nk], bq[1][1], accs[1][nk], 0, 0, 0);
            }
        }
        __builtin_amdgcn_s_setprio(0);

        // ---- P = 2^S, v_perm trunc pack (self-normalizing), per q-tile ----
        short8 pa[2][2];
#pragma unroll
        for (int mi = 0; mi < 2; ++mi) {
            float p[4][4];
#pragma unroll
            for (int nk = 0; nk < 4; ++nk)
#pragma unroll
                for (int r = 0; r < 4; ++r)
                    p[nk][r] = __builtin_amdgcn_exp2f(accs[mi][nk][r]);
#pragma unroll
            for (int ks = 0; ks < 2; ++ks) {
                union { short8 s8; unsigned u[4]; } pk;
                pk.u[0] = pk_hi16(p[2*ks][0],   p[2*ks][1]);
                pk.u[1] = pk_hi16(p[2*ks][2],   p[2*ks][3]);
                pk.u[2] = pk_hi16(p[2*ks+1][0], p[2*ks+1][1]);
                pk.u[3] = pk_hi16(p[2*ks+1][2], p[2*ks+1][3]);
                pa[mi][ks] = pk.s8;
            }
        }

        // ---- O += P V ; row-sum += P @ ones : one bv read, 2 MFMAs ----
        __builtin_amdgcn_s_setprio(1);
#pragma unroll
        for (int ks = 0; ks < 2; ++ks) {
            short8 bv[4];
#pragma unroll
            for (int dn = 0; dn < 4; ++dn) {
                const int row = dn * 16 + lr;
                bv[dn] = *(const short8*)(
                    Vs[buf] + row * 64 + (((ks << 2) | lg) ^ (row & 7)) * 8);
            }
            accp[0] = __builtin_amdgcn_mfma_f32_16x16x32_bf16(
                pa[0][ks], ones, accp[0], 0, 0, 0);
            accp[1] = __builtin_amdgcn_mfma_f32_16x16x32_bf16(
                pa[1][ks], ones, accp[1], 0, 0, 0);
#pragma unroll
            for (int dn = 0; dn < 4; ++dn) {
                acco[0][dn] = __builtin_amdgcn_mfma_f32_16x16x32_bf16(
                    pa[0][ks], bv[dn], acco[0][dn], 0, 0, 0);
                acco[1][dn] = __builtin_amdgcn_mfma_f32_16x16x32_bf16(
                    pa[1][ks], bv[dn], acco[1][dn], 0, 0, 0);
            }
        }
        __builtin_amdgcn_s_setprio(0);

        // ---- counted pipeline; unclamped kt+2 (dead loads stay in-buffer) --
        __builtin_amdgcn_s_barrier();
        STAGE(buf, kt + 2);
        asm volatile("s_waitcnt vmcnt(4)" ::: "memory");
        __builtin_amdgcn_sched_barrier(0);
        __builtin_amdgcn_s_barrier();
    }

#pragma unroll
    for (int mi = 0; mi < 2; ++mi) {
#pragma unroll
        for (int r = 0; r < 4; ++r) {
            const float invl = 1.f / accp[mi][r];
            const int qq = q0 + mi * 16 + lg * 4 + r;
            ushort_t* dst = O + (size_t)(n * LL + qq) * EE + h * HDD + lr;
#pragma unroll
            for (int dn = 0; dn < 4; ++dn)
                dst[dn * 16] = f2bf(acco[mi][dn][r] * invl);
        }
    }
#undef STAGE
}

// ---------------------------------------------------------------------------
// Transpose+convert: in f32 [K][N] -> out bf16 [N][K]
// ---------------------------------------------------------------------------
__global__ __launch_bounds__(256) void tcvt(
    const float* __restrict__ in, ushort_t* __restrict__ out, int K, int N)
{
    __shared__ float T[32][36];
    const int n0 = blockIdx.x * 32, k0 = blockIdx.y * 32;
    const int r = threadIdx.x >> 3, c4 = (threadIdx.x & 7) * 4;
    const float4 v = *(const float4*)(in + (size_t)(k0 + r) * N + n0 + c4);
    T[r][c4] = v.x; T[r][c4 + 1] = v.y; T[r][c4 + 2] = v.z; T[r][c4 + 3] = v.w;
    __syncthreads();
    const unsigned a = f2bf(T[c4][r])     | ((unsigned)f2bf(T[c4 + 1][r]) << 16);
    const unsigned b = f2bf(T[c4 + 2][r]) | ((unsigned)f2bf(T[c4 + 3][r]) << 16);
    uint2 pk; pk.x = a; pk.y = b;
    *(uint2*)(out + (size_t)(n0 + r) * K + k0 + c4) = pk;
}

// ---------------------------------------------------------------------------
// 8-phase 256x256 bf16 MFMA GEMM (ffn1): C = relu(A @ Bt^T + bias), bf16 out.
// ---------------------------------------------------------------------------
__global__ __launch_bounds__(512, 2) void gemm8p(
    const ushort_t* __restrict__ A, const ushort_t* __restrict__ Bt,
    const float* __restrict__ bias, ushort_t* __restrict__ C,
    int M, int N, int K)
{
    __shared__ __align__(16) ushort_t L[2][4][256 * 32];  // 128 KiB

    const int tid = threadIdx.x;
    const int w = tid >> 6, l = tid & 63;
    const int fr = l & 15, lg = l >> 4;
    const int wr = w >> 2, wc = w & 3;

    const int gx = gridDim.x;
    const int nwg = gx * gridDim.y;
    const int bid = blockIdx.y * gx + blockIdx.x;
    int tile = bid;
    if ((nwg & 7) == 0) tile = (bid & 7) * (nwg >> 3) + (bid >> 3);
    const int bx = tile % gx, by = tile / gx;
    const int brow = by * 256, bcol = bx * 256;

    const int NT = K >> 6;
    const int UMAX = NT << 2;

#define STAGE8(u)                                                              \
    if ((u) < UMAX) {                                                          \
        const int tt = (u) >> 2, slot = (u) & 3;                               \
        const int op = slot & 1, kh = slot >> 1;                               \
        const ushort_t* sp = op ? Bt : A;                                      \
        const int rb = op ? bcol : brow;                                       \
        ushort_t* db = (ushort_t*)L[tt & 1][slot];                             \
        _Pragma("unroll")                                                      \
        for (int j = 0; j < 2; ++j) {                                          \
            const int id = j * 512 + tid;                                      \
            const int row = id >> 2, c = id & 3;                               \
            const int cs = c ^ ((row >> 1) & 3);                               \
            gload16(sp + (size_t)(rb + row) * K + tt * 64 + kh * 32 + cs * 8,  \
                    (void*)(db + id * 8));                                     \
        }                                                                      \
    }

    f32x4 acc[8][4];
#pragma unroll
    for (int i = 0; i < 8; ++i)
#pragma unroll
        for (int g = 0; g < 4; ++g) { f32x4 zz = {0.f,0.f,0.f,0.f}; acc[i][g] = zz; }

#pragma unroll
    for (int u = 0; u < 6; ++u) STAGE8(u);
    asm volatile("s_waitcnt vmcnt(4)" ::: "memory");
    __builtin_amdgcn_sched_barrier(0);
    __builtin_amdgcn_s_barrier();

    const int iters = NT >> 1;
    for (int it = 0; it < iters; ++it) {
#pragma unroll
        for (int p = 0; p < 8; ++p) {
            STAGE8(it * 8 + p + 6);
            const int d  = p >> 2;
            const int mh = p & 1, kh = (p >> 1) & 1;
            short8 af[4], bfr[4];
#pragma unroll
            for (int f = 0; f < 4; ++f) {
                const int row = wr * 128 + (mh * 4 + f) * 16 + fr;
                const int ch = lg ^ ((row >> 1) & 3);
                af[f] = *(const short8*)(&L[d][kh * 2][row * 32 + ch * 8]);
            }
#pragma unroll
            for (int g = 0; g < 4; ++g) {
                const int row = wc * 64 + g * 16 + fr;
                const int ch = lg ^ ((row >> 1) & 3);
                bfr[g] = *(const short8*)(&L[d][kh * 2 + 1][row * 32 + ch * 8]);
            }
            __builtin_amdgcn_s_barrier();
            __builtin_amdgcn_s_setprio(1);
#pragma unroll
            for (int f = 0; f < 4; ++f)
#pragma unroll
                for (int g = 0; g < 4; ++g)
                    acc[mh * 4 + f][g] = __builtin_amdgcn_mfma_f32_16x16x32_bf16(
                        af[f], bfr[g], acc[mh * 4 + f][g], 0, 0, 0);
            __builtin_amdgcn_s_setprio(0);
            if (p == 3 || p == 7) {
                asm volatile("s_waitcnt vmcnt(4)" ::: "memory");
                __builtin_amdgcn_sched_barrier(0);
            }
            __builtin_amdgcn_s_barrier();
        }
    }

#pragma unroll
    for (int mi = 0; mi < 8; ++mi) {
#pragma unroll
        for (int g = 0; g < 4; ++g) {
            const int col = bcol + wc * 64 + g * 16 + fr;
            const float bv = bias[col];
#pragma unroll
            for (int r = 0; r < 4; ++r) {
                const int row = brow + wr * 128 + mi * 16 + lg * 4 + r;
                const float v = fmaxf(acc[mi][g][r] + bv, 0.f);
                C[(size_t)row * N + col] = f2bf(v);
            }
        }
    }
#undef STAGE8
}

// ---------------------------------------------------------------------------
// 8-phase 256x128 bf16 MFMA GEMM, split-K partials (proj & ffn2).
// LDS 96KB: per dbuf {A_k0 16K | B_k0 8K | A_k1 16K | B_k1 8K}.
// Loads/thread: A-slot 2, B-slot 1 -> tile = 6; counted vmcnt(3).
// ---------------------------------------------------------------------------
#define SOFF(slot) ((slot) == 0 ? 0 : (slot) == 1 ? 8192 : (slot) == 2 ? 12288 : 20480)

template <int KSPLIT>
__global__ __launch_bounds__(512, 2) void gemm8p_n128(
    const ushort_t* __restrict__ A, const ushort_t* __restrict__ Bt,
    ushort_t* __restrict__ C, int M, int N, int K)
{
    __shared__ __align__(16) ushort_t L[2][24576];  // 96 KiB

    const int tid = threadIdx.x;
    const int w = tid >> 6, l = tid & 63;
    const int fr = l & 15, lg = l >> 4;
    const int wr = w >> 2, wc = w & 3;

    const int z = blockIdx.z;
    const int Keff = K / KSPLIT;
    const int kb = z * Keff;

    const int gx = gridDim.x;
    const int nwg = gx * gridDim.y;
    const int bid = blockIdx.y * gx + blockIdx.x;
    int tile = bid;
    if ((nwg & 7) == 0) tile = (bid & 7) * (nwg >> 3) + (bid >> 3);
    const int bx = tile % gx, by = tile / gx;
    const int brow = by * 256, bcol = bx * 128;

    const int NT = Keff >> 6;
    const int UMAX = NT << 2;

#define STG(u)                                                                 \
    if ((u) < UMAX) {                                                          \
        const int tt = (u) >> 2, slot = (u) & 3;                               \
        const int op = slot & 1, kh = slot >> 1;                               \
        const ushort_t* sp = op ? Bt : A;                                      \
        const int rb = op ? bcol : brow;                                       \
        ushort_t* db = (ushort_t*)L[tt & 1] + SOFF(slot);                      \
        const int nld = op ? 1 : 2;                                            \
        _Pragma("unroll")                                                      \
        for (int j = 0; j < nld; ++j) {                                        \
            const int id = j * 512 + tid;                                      \
            const int row = id >> 2, c = id & 3;                               \
            const int cs = c ^ ((row >> 1) & 3);                               \
            gload16(sp + (size_t)(rb + row) * K + kb + tt * 64 + kh * 32 + cs * 8, \
                    (void*)(db + id * 8));                                     \
        }                                                                      \
    }

    f32x4 acc[8][2];
#pragma unroll
    for (int i = 0; i < 8; ++i)
#pragma unroll
        for (int g = 0; g < 2; ++g) { f32x4 zz = {0.f,0.f,0.f,0.f}; acc[i][g] = zz; }

#pragma unroll
    for (int u = 0; u < 6; ++u) STG(u);
    asm volatile("s_waitcnt vmcnt(3)" ::: "memory");
    __builtin_amdgcn_sched_barrier(0);
    __builtin_amdgcn_s_barrier();

    const int iters = NT >> 1;
    for (int it = 0; it < iters; ++it) {
#pragma unroll
        for (int p = 0; p < 8; ++p) {
            STG(it * 8 + p + 6);
            const int d  = p >> 2;
            const int mh = p & 1, kh = (p >> 1) & 1;
            short8 af[4], bfr[2];
#pragma unroll
            for (int f = 0; f < 4; ++f) {
                const int row = wr * 128 + (mh * 4 + f) * 16 + fr;
                const int ch = lg ^ ((row >> 1) & 3);
                af[f] = *(const short8*)(&L[d][SOFF(kh * 2) + row * 32 + ch * 8]);
            }
#pragma unroll
            for (int g = 0; g < 2; ++g) {
                const int row = wc * 32 + g * 16 + fr;
                const int ch = lg ^ ((row >> 1) & 3);
                bfr[g] = *(const short8*)(&L[d][SOFF(kh * 2 + 1) + row * 32 + ch * 8]);
            }
            __builtin_amdgcn_s_barrier();
            __builtin_amdgcn_s_setprio(1);
#pragma unroll
            for (int f = 0; f < 4; ++f)
#pragma unroll
                for (int g = 0; g < 2; ++g)
                    acc[mh * 4 + f][g] = __builtin_amdgcn_mfma_f32_16x16x32_bf16(
                        af[f], bfr[g], acc[mh * 4 + f][g], 0, 0, 0);
            __builtin_amdgcn_s_setprio(0);
            if (p == 3 || p == 7) {
                asm volatile("s_waitcnt vmcnt(3)" ::: "memory");
                __builtin_amdgcn_sched_barrier(0);
            }
            __builtin_amdgcn_s_barrier();
        }
    }

    ushort_t* Cb = C + (size_t)z * M * N;
#pragma unroll
    for (int mi = 0; mi < 8; ++mi) {
#pragma unroll
        for (int g = 0; g < 2; ++g) {
            const int col = bcol + wc * 32 + g * 16 + fr;
#pragma unroll
            for (int r = 0; r < 4; ++r) {
                const int row = brow + wr * 128 + mi * 16 + lg * 4 + r;
                Cb[(size_t)row * N + col] = f2bf(acc[mi][g][r]);
            }
        }
    }
#undef STG
}

// ---------------------------------------------------------------------------
// LN1: x = LN(p0 + p1 + b_out + query), p bf16 / query f32; bf16 out.
// ---------------------------------------------------------------------------
__global__ __launch_bounds__(256) void ln_mid(
    const ushort_t* __restrict__ y0, const ushort_t* __restrict__ y1,
    const float* __restrict__ qres, const float* __restrict__ b0,
    const float* __restrict__ g, const float* __restrict__ b,
    ushort_t* __restrict__ out)
{
    const int row = blockIdx.x;
    const int t = threadIdx.x;
    const size_t off = (size_t)row * EE;
    const uint2 a = ((const uint2*)(y0 + off))[t];
    const uint2 c = ((const uint2*)(y1 + off))[t];
    const float4 qq = ((const float4*)(qres + off))[t];
    const float4 b04 = ((const float4*)b0)[t];
    float x[4];
    x[0] = bf2f(a.x & 0xffff) + bf2f(c.x & 0xffff) + qq.x + b04.x;
    x[1] = bf2f(a.x >> 16)    + bf2f(c.x >> 16)    + qq.y + b04.y;
    x[2] = bf2f(a.y & 0xffff) + bf2f(c.y & 0xffff) + qq.z + b04.z;
    x[3] = bf2f(a.y >> 16)    + bf2f(c.y >> 16)    + qq.w + b04.w;

    float s = 0.f, ss = 0.f;
#pragma unroll
    for (int i = 0; i < 4; ++i) { s += x[i]; ss += x[i] * x[i]; }
#pragma unroll
    for (int o = 1; o < 64; o <<= 1) {
        s  += __shfl_xor(s, o, 64);
        ss += __shfl_xor(ss, o, 64);
    }
    __shared__ float sm[8];
    const int wid = t >> 6;
    if ((t & 63) == 0) { sm[wid * 2] = s; sm[wid * 2 + 1] = ss; }
    __syncthreads();
    const float stot  = sm[0] + sm[2] + sm[4] + sm[6];
    const float sstot = sm[1] + sm[3] + sm[5] + sm[7];
    const float mu  = stot * (1.f / EE);
    const float inv = rsqrtf(sstot * (1.f / EE) - mu * mu + LN_EPS);

    const float4 gg = ((const float4*)g)[t];
    const float4 bb = ((const float4*)b)[t];
    uint2 pk;
    pk.x = f2bf((x[0] - mu) * inv * gg.x + bb.x) |
           ((unsigned)f2bf((x[1] - mu) * inv * gg.y + bb.y) << 16);
    pk.y = f2bf((x[2] - mu) * inv * gg.z + bb.z) |
           ((unsigned)f2bf((x[3] - mu) * inv * gg.w + bb.w) << 16);
    ((uint2*)(out + off))[t] = pk;
}

// ---------------------------------------------------------------------------
// LN2: out = LN(y0 + y1 + b2 + x), all-bf16 inputs, f32 out.
// ---------------------------------------------------------------------------
__global__ __launch_bounds__(256) void ln_out(
    const ushort_t* __restrict__ y0, const ushort_t* __restrict__ y1,
    const ushort_t* __restrict__ xb, const float* __restrict__ b2,
    const float* __restrict__ g, const float* __restrict__ be,
    float* __restrict__ out)
{
    const int row = blockIdx.x;
    const int t = threadIdx.x;
    const size_t off = (size_t)row * EE;
    const uint2 a = ((const uint2*)(y0 + off))[t];
    const uint2 b = ((const uint2*)(y1 + off))[t];
    const uint2 c = ((const uint2*)(xb + off))[t];
    const float4 bb2 = ((const float4*)b2)[t];
    float x[4];
    x[0] = bf2f(a.x & 0xffff) + bf2f(b.x & 0xffff) + bf2f(c.x & 0xffff) + bb2.x;
    x[1] = bf2f(a.x >> 16)    + bf2f(b.x >> 16)    + bf2f(c.x >> 16)    + bb2.y;
    x[2] = bf2f(a.y & 0xffff) + bf2f(b.y & 0xffff) + bf2f(c.y & 0xffff) + bb2.z;
    x[3] = bf2f(a.y >> 16)    + bf2f(b.y >> 16)    + bf2f(c.y >> 16)    + bb2.w;

    float s = 0.f, ss = 0.f;
#pragma unroll
    for (int i = 0; i < 4; ++i) { s += x[i]; ss += x[i] * x[i]; }
#pragma unroll
    for (int o = 1; o < 64; o <<= 1) {
        s  += __shfl_xor(s, o, 64);
        ss += __shfl_xor(ss, o, 64);
    }
    __shared__ float sm[8];
    const int wid = t >> 6;
    if ((t & 63) == 0) { sm[wid * 2] = s; sm[wid * 2 + 1] = ss; }
    __syncthreads();
    const float stot  = sm[0] + sm[2] + sm[4] + sm[6];
    const float sstot = sm[1] + sm[3] + sm[5] + sm[7];
    const float mu  = stot * (1.f / EE);
    const float inv = rsqrtf(sstot * (1.f / EE) - mu * mu + LN_EPS);

    const float4 gg = ((const float4*)g)[t];
    const float4 bb = ((const float4*)be)[t];
    float4 o;
    o.x = (x[0] - mu) * inv * gg.x + bb.x;
    o.y = (x[1] - mu) * inv * gg.y + bb.y;
    o.z = (x[2] - mu) * inv * gg.z + bb.z;
    o.w = (x[3] - mu) * inv * gg.w + bb.w;
    ((float4*)(out + off))[t] = o;
}

// ---------------------------------------------------------------------------
extern "C" void kernel_launch(void* const* d_in, const int* in_sizes, int n_in,
                              void* d_out, int out_size, void* d_ws, size_t ws_size,
                              hipStream_t stream) {
    (void)in_sizes; (void)n_in; (void)out_size; (void)ws_size;
    const float* value = (const float*)d_in[0];
    const float* key   = (const float*)d_in[1];
    const float* query = (const float*)d_in[2];
    const float* w_out = (const float*)d_in[3];
    const float* b_out = (const float*)d_in[4];
    const float* w1    = (const float*)d_in[5];
    const float* b1    = (const float*)d_in[6];
    const float* w2    = (const float*)d_in[7];
    const float* b2    = (const float*)d_in[8];
    const float* g1    = (const float*)d_in[9];
    const float* be1   = (const float*)d_in[10];
    const float* g2    = (const float*)d_in[11];
    const float* be2   = (const float*)d_in[12];
    float* out = (float*)d_out;

    const int M = NB * LL;  // 4096
    char* base = (char*)d_ws;
    ushort_t* attn_bf = (ushort_t*)(base);                      //  8 MB
    ushort_t* x_bf    = (ushort_t*)(base + (8ull  << 20));      //  8 MB
    char*     hregion = base + (16ull << 20);                   // 32 MB
    ushort_t* h_bf    = (ushort_t*)hregion;                     //  (post-attn)
    ushort_t* Kh      = (ushort_t*)(hregion);                   //  8 MB (pre-attn)
    ushort_t* Vt      = (ushort_t*)(hregion + (8ull  << 20));   //  8 MB
    ushort_t* y01     = (ushort_t*)(base + (48ull << 20));      // 16 MB (2 partials)
    ushort_t* w0T     = (ushort_t*)(base + (64ull << 20));      //  2 MB
    ushort_t* w1T     = (ushort_t*)(base + (66ull << 20));      //  8 MB
    ushort_t* w2T     = (ushort_t*)(base + (74ull << 20));      //  8 MB (ends 82)

    tcvt<<<dim3(EE / 32, EE / 32), 256, 0, stream>>>(w_out, w0T, EE, EE);
    tcvt<<<dim3(FFD / 32, EE / 32), 256, 0, stream>>>(w1, w1T, EE, FFD);
    tcvt<<<dim3(EE / 32, FFD / 32), 256, 0, stream>>>(w2, w2T, FFD, EE);

    k_cvt<<<NB * HH * LL / 32, 256, 0, stream>>>(key, Kh);
    v_cvt_t<<<dim3(LL / 64, HH, NB), 256, 0, stream>>>(value, Vt);

    attn_mfma<<<dim3(NB * HH * LL / 128), 256, 0, stream>>>(query, Kh, Vt,
                                                            attn_bf);

    // proj: split-K=2 partials (8-phase 256x128), bias+residual fused in LN1
    gemm8p_n128<2><<<dim3(EE / 128, M / 256, 2), 512, 0, stream>>>(
        attn_bf, w0T, y01, M, EE, EE);
    ln_mid<<<M, 256, 0, stream>>>(y01, y01 + (size_t)M * EE, query, b_out,
                                  g1, be1, x_bf);

    // ffn1: [4096,4096] = relu(x_bf @ w1T + b1), bf16 out (8-phase 256x256)
    gemm8p<<<dim3(FFD / 256, M / 256), 512, 0, stream>>>(x_bf, w1T, b1, h_bf,
                                                         M, FFD, EE);
    // ffn2: split-K=2 partials (8-phase 256x128)
    gemm8p_n128<2><<<dim3(EE / 128, M / 256, 2), 512, 0, stream>>>(
        h_bf, w2T, y01, M, EE, FFD);
    ln_out<<<M, 256, 0, stream>>>(y01, y01 + (size_t)M * EE, x_bf, b2, g2, be2,
                                  out);
}